// Round 1
// baseline (1618.050 us; speedup 1.0000x reference)
//
#include <hip/hip_runtime.h>
#include <cmath>

#define NSP 119
#define UNITS 512
#define NFEAT 360

// ---------- constant index tables ----------
__constant__ int T2I[15] = {0,1,1,2,2,2,3,3,3,3,4,4,4,4,4};
__constant__ int T2J[15] = {0,0,1,0,1,2,0,1,2,3,0,1,2,3,4};
__constant__ int T3A[35] = {0, 1,1,1, 2,2,2,2,2,2, 3,3,3,3,3,3,3,3,3,3, 4,4,4,4,4,4,4,4,4,4,4,4,4,4,4};
__constant__ int T3B[35] = {0, 0,1,1, 0,1,1,2,2,2, 0,1,1,2,2,2,3,3,3,3, 0,1,1,2,2,2,3,3,3,3,4,4,4,4,4};
__constant__ int T3C[35] = {0, 0,0,1, 0,0,1,0,1,2, 0,0,1,0,1,2,0,1,2,3, 0,0,1,0,1,2,0,1,2,3,0,1,2,3,4};

// ---------- phase 1: per-pair moments, atomic accumulate (unique sym components) ----------
// M layout per atom (100 floats): M0[5] | M1[5][3] | M2u[5][6] | M3u[5][10]
__global__ __launch_bounds__(256) void pair_kernel(
    const float* __restrict__ R, const int* __restrict__ Z,
    const int* __restrict__ nbr, const float* __restrict__ offsets,
    const float* __restrict__ emb, float* __restrict__ Mbuf, int npairs)
{
    int p = blockIdx.x * 256 + threadIdx.x;
    if (p >= npairs) return;
    int i = nbr[p];
    int j = nbr[npairs + p];
    float dx = R[3*j]   - R[3*i]   + offsets[3*p];
    float dy = R[3*j+1] - R[3*i+1] + offsets[3*p+1];
    float dz = R[3*j+2] - R[3*i+2] + offsets[3*p+2];
    float dr = sqrtf(dx*dx + dy*dy + dz*dz);
    if (!(dr < 6.0f)) return;   // cutoff factor is exactly 0 -> no contribution

    float inv = 1.0f / (dr + 1e-5f);
    float d0 = dx*inv, d1 = dy*inv, d2 = dz*inv;
    float cutoff = 0.5f * (cosf(0.523598775598299f * dr) + 1.0f); // pi/R_MAX

    const float betta = 49.0f / 36.0f;
    const float rad_norm = expf(0.75f * logf(2.0f * betta / 3.14159265358979f));
    float basis[7];
    #pragma unroll
    for (int b = 0; b < 7; ++b) {
        float sh = 0.5f + b * (5.5f / 6.0f);
        float d = dr - sh;
        basis[b] = rad_norm * expf(-betta * d * d);
    }
    const float* e = emb + ((size_t)Z[j] * NSP + Z[i]) * 35;
    const float EMBN = 0.377964473009227f; // 1/sqrt(7)
    float rad[5];
    #pragma unroll
    for (int r = 0; r < 5; ++r) {
        float s = 0.f;
        #pragma unroll
        for (int b = 0; b < 7; ++b) s += e[r*7 + b] * basis[b];
        rad[r] = EMBN * s * cutoff;
    }
    // unique symmetric products of dn
    float p2[6]  = {d0*d0, d1*d0, d1*d1, d2*d0, d2*d1, d2*d2};
    float p3[10] = {d0*d0*d0, d1*d0*d0, d1*d1*d0, d1*d1*d1,
                    d2*d0*d0, d2*d1*d0, d2*d1*d1, d2*d2*d0, d2*d2*d1, d2*d2*d2};
    float dn[3] = {d0, d1, d2};
    float* Ma = Mbuf + (size_t)i * 100;
    #pragma unroll
    for (int r = 0; r < 5; ++r) {
        float rv = rad[r];
        atomicAdd(Ma + r, rv);
        #pragma unroll
        for (int x = 0; x < 3; ++x)  atomicAdd(Ma + 5  + r*3  + x, rv * dn[x]);
        #pragma unroll
        for (int c = 0; c < 6; ++c)  atomicAdd(Ma + 20 + r*6  + c, rv * p2[c]);
        #pragma unroll
        for (int c = 0; c < 10; ++c) atomicAdd(Ma + 50 + r*10 + c, rv * p3[c]);
    }
}

// ---------- phase 2: per-atom contractions -> 360 features ----------
__global__ __launch_bounds__(64) void feat_kernel(
    const float* __restrict__ Mbuf, float* __restrict__ feats)
{
    int a = blockIdx.x;
    int tid = threadIdx.x;
    __shared__ float raw[100];
    __shared__ float F[200]; // M0[5] | M1[15] | M2 full[45] | M3 full[135]
    const float* src = Mbuf + (size_t)a * 100;
    for (int idx = tid; idx < 100; idx += 64) raw[idx] = src[idx];
    __syncthreads();
    for (int idx = tid; idx < 200; idx += 64) {
        float v;
        if (idx < 20) {
            v = raw[idx];
        } else if (idx < 65) {
            int rel = idx - 20, r = rel / 9, q = rel % 9, x = q / 3, y = q % 3;
            int hi = max(x, y), lo = min(x, y);
            v = raw[20 + r*6 + hi*(hi+1)/2 + lo];
        } else {
            int rel = idx - 65, r = rel / 27, q = rel % 27;
            int x = q / 9, y = (q / 3) % 3, z = q % 3;
            int A = max(x, max(y, z)), C = min(x, min(y, z)), B = x + y + z - A - C;
            v = raw[50 + r*10 + A*(A+1)*(A+2)/6 + B*(B+1)/2 + C];
        }
        F[idx] = v;
    }
    __syncthreads();
    const float* M0 = F;
    const float* M1 = F + 5;    // [r*3+x]
    const float* M2 = F + 20;   // [r*9+x*3+y]
    const float* M3 = F + 65;   // [r*27+x*9+y*3+z]
    float* out = feats + (size_t)a * NFEAT;
    for (int f = tid; f < NFEAT; f += 64) {
        float v = 0.f;
        if (f < 5) {
            v = M0[f];
        } else if (f < 20) {                 // c1
            int p = f - 5, r = T2I[p], s = T2J[p];
            for (int x = 0; x < 3; ++x) v += M1[r*3+x] * M1[s*3+x];
        } else if (f < 35) {                 // c2
            int p = f - 20, r = T2I[p], s = T2J[p];
            for (int q = 0; q < 9; ++q) v += M2[r*9+q] * M2[s*9+q];
        } else if (f < 50) {                 // c3
            int p = f - 35, r = T2I[p], s = T2J[p];
            for (int q = 0; q < 27; ++q) v += M3[r*27+q] * M3[s*27+q];
        } else if (f < 85) {                 // c4: sum M2[r,x,y] M2[s,x,z] M2[t,y,z]
            int q = f - 50, r = T3A[q], s = T3B[q], t = T3C[q];
            for (int x = 0; x < 3; ++x)
                for (int y = 0; y < 3; ++y)
                    for (int z = 0; z < 3; ++z)
                        v += M2[r*9+x*3+y] * M2[s*9+x*3+z] * M2[t*9+y*3+z];
        } else if (f < 160) {                // c5: sum M1[r,x] M1[s,y] M2[t,x,y]
            int q = f - 85, p = q / 5, t = q % 5, r = T2I[p], s = T2J[p];
            for (int x = 0; x < 3; ++x)
                for (int y = 0; y < 3; ++y)
                    v += M1[r*3+x] * M1[s*3+y] * M2[t*9+x*3+y];
        } else if (f < 235) {                // c6: sum M3[r,x,y,z] M3[s,x,y,w] M2[t,z,w]
            int q = f - 160, p = q / 5, t = q % 5, r = T2I[p], s = T2J[p];
            for (int z = 0; z < 3; ++z)
                for (int w = 0; w < 3; ++w) {
                    float bs = 0.f;
                    for (int x = 0; x < 3; ++x)
                        for (int y = 0; y < 3; ++y)
                            bs += M3[r*27+x*9+y*3+z] * M3[s*27+x*9+y*3+w];
                    v += bs * M2[t*9+z*3+w];
                }
        } else {                             // c7: sum M3[r,x,y,z] M2[s,x,y] M1[t,z]
            int q = f - 235, r = q / 25, s = (q / 5) % 5, t = q % 5;
            for (int z = 0; z < 3; ++z) {
                float bs = 0.f;
                for (int x = 0; x < 3; ++x)
                    for (int y = 0; y < 3; ++y)
                        bs += M3[r*27+x*9+y*3+z] * M2[s*9+x*3+y];
                v += bs * M1[t*3+z];
            }
        }
        out[f] = v;
    }
}

// ---------- fp32 tiled GEMM: C = swish(alpha*A@B + 0.1*bias) ----------
#define BM 64
#define BN 64
#define BK 8

__global__ __launch_bounds__(256) void gemm_swish(
    const float* __restrict__ A, const float* __restrict__ B,
    const float* __restrict__ bias, float* __restrict__ C,
    int M, int N, int K, float alpha)
{
    __shared__ float As[BK][BM + 8];
    __shared__ float Bs[BK][BN + 8];
    int tid = threadIdx.x;
    int tx = tid & 15, ty = tid >> 4;
    int rowBase = blockIdx.x * BM, colBase = blockIdx.y * BN;
    float acc[4][4] = {};
    int kA = tid & 7, mA = tid >> 3;
    int nB = tid & 63, kB = tid >> 6;
    for (int k0 = 0; k0 < K; k0 += BK) {
        #pragma unroll
        for (int i = 0; i < 2; ++i) {
            int m = mA + i * 32;
            int row = rowBase + m;
            As[kA][m] = (row < M) ? A[(size_t)row * K + k0 + kA] : 0.f;
        }
        #pragma unroll
        for (int i = 0; i < 2; ++i) {
            int k = kB + i * 4;
            Bs[k][nB] = B[(size_t)(k0 + k) * N + colBase + nB];
        }
        __syncthreads();
        #pragma unroll
        for (int kk = 0; kk < BK; ++kk) {
            float4 av = *reinterpret_cast<float4*>(&As[kk][ty << 2]);
            float4 bv = *reinterpret_cast<float4*>(&Bs[kk][tx << 2]);
            float a[4] = {av.x, av.y, av.z, av.w};
            float b[4] = {bv.x, bv.y, bv.z, bv.w};
            #pragma unroll
            for (int mi = 0; mi < 4; ++mi)
                #pragma unroll
                for (int ni = 0; ni < 4; ++ni)
                    acc[mi][ni] += a[mi] * b[ni];
        }
        __syncthreads();
    }
    #pragma unroll
    for (int mi = 0; mi < 4; ++mi) {
        int row = rowBase + (ty << 2) + mi;
        if (row >= M) continue;
        #pragma unroll
        for (int ni = 0; ni < 4; ++ni) {
            int col = colBase + (tx << 2) + ni;
            float x = alpha * acc[mi][ni] + 0.1f * bias[col];
            C[(size_t)row * N + col] = x / (1.f + expf(-x));
        }
    }
}

// ---------- layer2 + fused W3 dot: atomicAdd partial row dots into out ----------
__global__ __launch_bounds__(256) void gemm_swish_w3(
    const float* __restrict__ A, const float* __restrict__ B,
    const float* __restrict__ bias, const float* __restrict__ W3,
    float* __restrict__ outacc, int M, int N, int K, float alpha, float alpha3)
{
    __shared__ float As[BK][BM + 8];
    __shared__ float Bs[BK][BN + 8];
    int tid = threadIdx.x;
    int tx = tid & 15, ty = tid >> 4;
    int rowBase = blockIdx.x * BM, colBase = blockIdx.y * BN;
    float acc[4][4] = {};
    int kA = tid & 7, mA = tid >> 3;
    int nB = tid & 63, kB = tid >> 6;
    for (int k0 = 0; k0 < K; k0 += BK) {
        #pragma unroll
        for (int i = 0; i < 2; ++i) {
            int m = mA + i * 32;
            int row = rowBase + m;
            As[kA][m] = (row < M) ? A[(size_t)row * K + k0 + kA] : 0.f;
        }
        #pragma unroll
        for (int i = 0; i < 2; ++i) {
            int k = kB + i * 4;
            Bs[k][nB] = B[(size_t)(k0 + k) * N + colBase + nB];
        }
        __syncthreads();
        #pragma unroll
        for (int kk = 0; kk < BK; ++kk) {
            float4 av = *reinterpret_cast<float4*>(&As[kk][ty << 2]);
            float4 bv = *reinterpret_cast<float4*>(&Bs[kk][tx << 2]);
            float a[4] = {av.x, av.y, av.z, av.w};
            float b[4] = {bv.x, bv.y, bv.z, bv.w};
            #pragma unroll
            for (int mi = 0; mi < 4; ++mi)
                #pragma unroll
                for (int ni = 0; ni < 4; ++ni)
                    acc[mi][ni] += a[mi] * b[ni];
        }
        __syncthreads();
    }
    float w3s[4];
    #pragma unroll
    for (int ni = 0; ni < 4; ++ni) w3s[ni] = W3[colBase + (tx << 2) + ni] * alpha3;
    float rs[4];
    #pragma unroll
    for (int mi = 0; mi < 4; ++mi) {
        float s = 0.f;
        #pragma unroll
        for (int ni = 0; ni < 4; ++ni) {
            int col = colBase + (tx << 2) + ni;
            float x = alpha * acc[mi][ni] + 0.1f * bias[col];
            float v = x / (1.f + expf(-x));
            s += v * w3s[ni];
        }
        rs[mi] = s;
    }
    #pragma unroll
    for (int mi = 0; mi < 4; ++mi) {
        #pragma unroll
        for (int off = 1; off < 16; off <<= 1)
            rs[mi] += __shfl_xor(rs[mi], off, 64);
    }
    if (tx == 0) {
        #pragma unroll
        for (int mi = 0; mi < 4; ++mi) {
            int row = rowBase + (ty << 2) + mi;
            if (row < M) atomicAdd(&outacc[row], rs[mi]);
        }
    }
}

__global__ void finalize_kernel(float* __restrict__ out, const int* __restrict__ Z,
                                const float* __restrict__ b3, int natoms)
{
    int a = blockIdx.x * 256 + threadIdx.x;
    if (a >= natoms) return;
    float v = out[a] + 0.1f * b3[0];
    out[a] = (Z[a] > 0) ? v : 0.f;
}

extern "C" void kernel_launch(void* const* d_in, const int* in_sizes, int n_in,
                              void* d_out, int out_size, void* d_ws, size_t ws_size,
                              hipStream_t stream)
{
    const float* R       = (const float*)d_in[0];
    const int*   Z       = (const int*)  d_in[1];
    const int*   nbr     = (const int*)  d_in[2];
    // d_in[3] = box (unused)
    const float* offsets = (const float*)d_in[4];
    const float* emb     = (const float*)d_in[5];
    const float* W1      = (const float*)d_in[6];
    const float* b1      = (const float*)d_in[7];
    const float* W2      = (const float*)d_in[8];
    const float* b2      = (const float*)d_in[9];
    const float* W3      = (const float*)d_in[10];
    const float* b3      = (const float*)d_in[11];

    int natoms = in_sizes[0] / 3;
    int npairs = in_sizes[2] / 2;

    float* Mbuf  = (float*)d_ws;                       // natoms*100
    float* feats = Mbuf  + (size_t)natoms * 100;       // natoms*360
    float* h1    = feats + (size_t)natoms * NFEAT;     // natoms*512

    hipMemsetAsync(Mbuf, 0, (size_t)natoms * 100 * sizeof(float), stream);
    hipMemsetAsync(d_out, 0, (size_t)natoms * sizeof(float), stream);

    pair_kernel<<<dim3((npairs + 255) / 256), 256, 0, stream>>>(
        R, Z, nbr, offsets, emb, Mbuf, npairs);

    feat_kernel<<<dim3(natoms), 64, 0, stream>>>(Mbuf, feats);

    dim3 grid1((natoms + BM - 1) / BM, UNITS / BN);
    float a1 = 1.0f / sqrtf((float)NFEAT);
    gemm_swish<<<grid1, 256, 0, stream>>>(feats, W1, b1, h1, natoms, UNITS, NFEAT, a1);

    float a2 = 1.0f / sqrtf((float)UNITS);
    gemm_swish_w3<<<grid1, 256, 0, stream>>>(h1, W2, b2, W3, (float*)d_out,
                                             natoms, UNITS, UNITS, a2, a2);

    finalize_kernel<<<dim3((natoms + 255) / 256), 256, 0, stream>>>(
        (float*)d_out, Z, b3, natoms);
}

// Round 2
// 524.332 us; speedup vs baseline: 3.0859x; 3.0859x over previous
//
#include <hip/hip_runtime.h>
#include <cmath>

#define NSP 119
#define UNITS 512
#define NFEAT 360
#define DBLK 128

// ---------- constant index tables ----------
__constant__ int T2I[15] = {0,1,1,2,2,2,3,3,3,3,4,4,4,4,4};
__constant__ int T2J[15] = {0,0,1,0,1,2,0,1,2,3,0,1,2,3,4};
__constant__ int T3A[35] = {0, 1,1,1, 2,2,2,2,2,2, 3,3,3,3,3,3,3,3,3,3, 4,4,4,4,4,4,4,4,4,4,4,4,4,4,4};
__constant__ int T3B[35] = {0, 0,1,1, 0,1,1,2,2,2, 0,1,1,2,2,2,3,3,3,3, 0,1,1,2,2,2,3,3,3,3,4,4,4,4,4};
__constant__ int T3C[35] = {0, 0,0,1, 0,0,1,0,1,2, 0,0,1,0,1,2,0,1,2,3, 0,0,1,0,1,2,0,1,2,3,0,1,2,3,4};
// unique symmetric component index tables
__constant__ int P2X[6] = {0,1,1,2,2,2};
__constant__ int P2Y[6] = {0,0,1,0,1,2};
__constant__ int P3X[10] = {0,1,1,1,2,2,2,2,2,2};
__constant__ int P3Y[10] = {0,0,1,1,0,1,1,2,2,2};
__constant__ int P3Z[10] = {0,0,0,1,0,0,1,0,1,2};

// ---------- phase 1a: histogram of in-cutoff pairs per center atom ----------
__global__ __launch_bounds__(256) void hist_kernel(
    const float* __restrict__ R, const int* __restrict__ nbr,
    const float* __restrict__ offsets, int* __restrict__ counts, int npairs)
{
    int p = blockIdx.x * 256 + threadIdx.x;
    if (p >= npairs) return;
    int i = nbr[p];
    int j = nbr[npairs + p];
    float dx = R[3*j]   - R[3*i]   + offsets[3*p];
    float dy = R[3*j+1] - R[3*i+1] + offsets[3*p+1];
    float dz = R[3*j+2] - R[3*i+2] + offsets[3*p+2];
    float dr2 = dx*dx + dy*dy + dz*dz;
    if (dr2 < 36.0f) atomicAdd(&counts[i], 1);
}

// ---------- phase 1b: exclusive scan (single block) ----------
__global__ __launch_bounds__(1024) void scan_kernel(
    const int* __restrict__ counts, int* __restrict__ offs,
    int* __restrict__ cursor, int n)
{
    __shared__ int tile[1024];
    __shared__ int carry;
    int tid = threadIdx.x;
    if (tid == 0) carry = 0;
    __syncthreads();
    for (int base = 0; base < n; base += 1024) {
        int idx = base + tid;
        int v = (idx < n) ? counts[idx] : 0;
        tile[tid] = v;
        __syncthreads();
        for (int off = 1; off < 1024; off <<= 1) {
            int t = (tid >= off) ? tile[tid - off] : 0;
            __syncthreads();
            tile[tid] += t;
            __syncthreads();
        }
        int excl = carry + tile[tid] - v;
        if (idx < n) { offs[idx] = excl; cursor[idx] = excl; }
        __syncthreads();
        if (tid == 1023) carry += tile[1023];
        __syncthreads();
    }
}

// ---------- phase 1c: scatter pair indices into per-atom segments ----------
__global__ __launch_bounds__(256) void scatter_kernel(
    const float* __restrict__ R, const int* __restrict__ nbr,
    const float* __restrict__ offsets, int* __restrict__ cursor,
    int* __restrict__ sorted, int npairs)
{
    int p = blockIdx.x * 256 + threadIdx.x;
    if (p >= npairs) return;
    int i = nbr[p];
    int j = nbr[npairs + p];
    float dx = R[3*j]   - R[3*i]   + offsets[3*p];
    float dy = R[3*j+1] - R[3*i+1] + offsets[3*p+1];
    float dz = R[3*j+2] - R[3*i+2] + offsets[3*p+2];
    float dr2 = dx*dx + dy*dy + dz*dz;
    if (dr2 < 36.0f) {
        int pos = atomicAdd(&cursor[i], 1);
        sorted[pos] = p;
    }
}

// ---------- phase 2: per-atom moment accumulation + contractions -> 360 features ----------
__global__ __launch_bounds__(DBLK) void accum_feat_kernel(
    const float* __restrict__ R, const int* __restrict__ Z,
    const int* __restrict__ nbr, const float* __restrict__ offsets,
    const float* __restrict__ emb, const int* __restrict__ sorted,
    const int* __restrict__ offs, const int* __restrict__ counts,
    float* __restrict__ feats, int npairs)
{
    int a = blockIdx.x;
    int tid = threadIdx.x;
    __shared__ float stage[DBLK][8];   // per-pair rad[5] | dn[3]
    __shared__ float raw[100];         // unique sym moments
    __shared__ float F[200];           // expanded full moments

    int start = offs[a];
    int cnt = counts[a];
    float Ri0 = R[3*a], Ri1 = R[3*a+1], Ri2 = R[3*a+2];
    int Zi = Z[a];

    // per-thread component decode (threads 0..99 own one moment component)
    int cr = 0, nf = 0, i0 = 0, i1 = 0, i2 = 0;
    if (tid < 5)        { cr = tid; nf = 0; }
    else if (tid < 20)  { int c = tid - 5;  cr = c / 3;  nf = 1; i0 = c % 3; }
    else if (tid < 50)  { int c = tid - 20; cr = c / 6;  int k = c % 6;  nf = 2; i0 = P2X[k]; i1 = P2Y[k]; }
    else if (tid < 100) { int c = tid - 50; cr = c / 10; int k = c % 10; nf = 3; i0 = P3X[k]; i1 = P3Y[k]; i2 = P3Z[k]; }

    float acc = 0.f;
    for (int base = 0; base < cnt; base += DBLK) {
        int m = min(DBLK, cnt - base);
        if (tid < m) {
            int p = sorted[start + base + tid];
            int j = nbr[npairs + p];
            float dx = R[3*j]   - Ri0 + offsets[3*p];
            float dy = R[3*j+1] - Ri1 + offsets[3*p+1];
            float dz = R[3*j+2] - Ri2 + offsets[3*p+2];
            float dr = sqrtf(dx*dx + dy*dy + dz*dz);
            float inv = 1.0f / (dr + 1e-5f);
            float cutoff = 0.5f * (cosf(0.523598775598299f * dr) + 1.0f); // pi/R_MAX
            const float betta = 49.0f / 36.0f;
            const float rad_norm = expf(0.75f * logf(2.0f * betta / 3.14159265358979f));
            float basis[7];
            #pragma unroll
            for (int b = 0; b < 7; ++b) {
                float sh = 0.5f + b * (5.5f / 6.0f);
                float d = dr - sh;
                basis[b] = rad_norm * expf(-betta * d * d);
            }
            const float* e = emb + ((size_t)Z[j] * NSP + Zi) * 35;
            const float EMBN = 0.377964473009227f; // 1/sqrt(7)
            #pragma unroll
            for (int r = 0; r < 5; ++r) {
                float s = 0.f;
                #pragma unroll
                for (int b = 0; b < 7; ++b) s += e[r*7 + b] * basis[b];
                stage[tid][r] = EMBN * s * cutoff;
            }
            stage[tid][5] = dx * inv;
            stage[tid][6] = dy * inv;
            stage[tid][7] = dz * inv;
        }
        __syncthreads();
        if (tid < 100) {
            for (int q = 0; q < m; ++q) {
                const float* s = stage[q];
                float v = s[cr];
                if (nf > 0) v *= s[5 + i0];
                if (nf > 1) v *= s[5 + i1];
                if (nf > 2) v *= s[5 + i2];
                acc += v;
            }
        }
        __syncthreads();
    }
    if (tid < 100) raw[tid] = acc;
    __syncthreads();

    // expand unique sym components -> full tensors
    for (int idx = tid; idx < 200; idx += DBLK) {
        float v;
        if (idx < 20) {
            v = raw[idx];
        } else if (idx < 65) {
            int rel = idx - 20, r = rel / 9, q = rel % 9, x = q / 3, y = q % 3;
            int hi = max(x, y), lo = min(x, y);
            v = raw[20 + r*6 + hi*(hi+1)/2 + lo];
        } else {
            int rel = idx - 65, r = rel / 27, q = rel % 27;
            int x = q / 9, y = (q / 3) % 3, z = q % 3;
            int A = max(x, max(y, z)), C = min(x, min(y, z)), B = x + y + z - A - C;
            v = raw[50 + r*10 + A*(A+1)*(A+2)/6 + B*(B+1)/2 + C];
        }
        F[idx] = v;
    }
    __syncthreads();

    const float* M0 = F;
    const float* M1 = F + 5;    // [r*3+x]
    const float* M2 = F + 20;   // [r*9+x*3+y]
    const float* M3 = F + 65;   // [r*27+x*9+y*3+z]
    float* out = feats + (size_t)a * NFEAT;
    for (int f = tid; f < NFEAT; f += DBLK) {
        float v = 0.f;
        if (f < 5) {
            v = M0[f];
        } else if (f < 20) {                 // c1
            int p = f - 5, r = T2I[p], s = T2J[p];
            for (int x = 0; x < 3; ++x) v += M1[r*3+x] * M1[s*3+x];
        } else if (f < 35) {                 // c2
            int p = f - 20, r = T2I[p], s = T2J[p];
            for (int q = 0; q < 9; ++q) v += M2[r*9+q] * M2[s*9+q];
        } else if (f < 50) {                 // c3
            int p = f - 35, r = T2I[p], s = T2J[p];
            for (int q = 0; q < 27; ++q) v += M3[r*27+q] * M3[s*27+q];
        } else if (f < 85) {                 // c4
            int q = f - 50, r = T3A[q], s = T3B[q], t = T3C[q];
            for (int x = 0; x < 3; ++x)
                for (int y = 0; y < 3; ++y)
                    for (int z = 0; z < 3; ++z)
                        v += M2[r*9+x*3+y] * M2[s*9+x*3+z] * M2[t*9+y*3+z];
        } else if (f < 160) {                // c5
            int q = f - 85, p = q / 5, t = q % 5, r = T2I[p], s = T2J[p];
            for (int x = 0; x < 3; ++x)
                for (int y = 0; y < 3; ++y)
                    v += M1[r*3+x] * M1[s*3+y] * M2[t*9+x*3+y];
        } else if (f < 235) {                // c6
            int q = f - 160, p = q / 5, t = q % 5, r = T2I[p], s = T2J[p];
            for (int z = 0; z < 3; ++z)
                for (int w = 0; w < 3; ++w) {
                    float bs = 0.f;
                    for (int x = 0; x < 3; ++x)
                        for (int y = 0; y < 3; ++y)
                            bs += M3[r*27+x*9+y*3+z] * M3[s*27+x*9+y*3+w];
                    v += bs * M2[t*9+z*3+w];
                }
        } else {                             // c7
            int q = f - 235, r = q / 25, s = (q / 5) % 5, t = q % 5;
            for (int z = 0; z < 3; ++z) {
                float bs = 0.f;
                for (int x = 0; x < 3; ++x)
                    for (int y = 0; y < 3; ++y)
                        bs += M3[r*27+x*9+y*3+z] * M2[s*9+x*3+y];
                v += bs * M1[t*3+z];
            }
        }
        out[f] = v;
    }
}

// ---------- fp32 tiled GEMM: C = swish(alpha*A@B + 0.1*bias) ----------
#define BM 64
#define BN 64
#define BK 8

__global__ __launch_bounds__(256) void gemm_swish(
    const float* __restrict__ A, const float* __restrict__ B,
    const float* __restrict__ bias, float* __restrict__ C,
    int M, int N, int K, float alpha)
{
    __shared__ float As[BK][BM + 8];
    __shared__ float Bs[BK][BN + 8];
    int tid = threadIdx.x;
    int tx = tid & 15, ty = tid >> 4;
    int rowBase = blockIdx.x * BM, colBase = blockIdx.y * BN;
    float acc[4][4] = {};
    int kA = tid & 7, mA = tid >> 3;
    int nB = tid & 63, kB = tid >> 6;
    for (int k0 = 0; k0 < K; k0 += BK) {
        #pragma unroll
        for (int i = 0; i < 2; ++i) {
            int m = mA + i * 32;
            int row = rowBase + m;
            As[kA][m] = (row < M) ? A[(size_t)row * K + k0 + kA] : 0.f;
        }
        #pragma unroll
        for (int i = 0; i < 2; ++i) {
            int k = kB + i * 4;
            Bs[k][nB] = B[(size_t)(k0 + k) * N + colBase + nB];
        }
        __syncthreads();
        #pragma unroll
        for (int kk = 0; kk < BK; ++kk) {
            float4 av = *reinterpret_cast<float4*>(&As[kk][ty << 2]);
            float4 bv = *reinterpret_cast<float4*>(&Bs[kk][tx << 2]);
            float a[4] = {av.x, av.y, av.z, av.w};
            float b[4] = {bv.x, bv.y, bv.z, bv.w};
            #pragma unroll
            for (int mi = 0; mi < 4; ++mi)
                #pragma unroll
                for (int ni = 0; ni < 4; ++ni)
                    acc[mi][ni] += a[mi] * b[ni];
        }
        __syncthreads();
    }
    #pragma unroll
    for (int mi = 0; mi < 4; ++mi) {
        int row = rowBase + (ty << 2) + mi;
        if (row >= M) continue;
        #pragma unroll
        for (int ni = 0; ni < 4; ++ni) {
            int col = colBase + (tx << 2) + ni;
            float x = alpha * acc[mi][ni] + 0.1f * bias[col];
            C[(size_t)row * N + col] = x / (1.f + expf(-x));
        }
    }
}

// ---------- layer2 + fused W3 dot: atomicAdd partial row dots into out ----------
__global__ __launch_bounds__(256) void gemm_swish_w3(
    const float* __restrict__ A, const float* __restrict__ B,
    const float* __restrict__ bias, const float* __restrict__ W3,
    float* __restrict__ outacc, int M, int N, int K, float alpha, float alpha3)
{
    __shared__ float As[BK][BM + 8];
    __shared__ float Bs[BK][BN + 8];
    int tid = threadIdx.x;
    int tx = tid & 15, ty = tid >> 4;
    int rowBase = blockIdx.x * BM, colBase = blockIdx.y * BN;
    float acc[4][4] = {};
    int kA = tid & 7, mA = tid >> 3;
    int nB = tid & 63, kB = tid >> 6;
    for (int k0 = 0; k0 < K; k0 += BK) {
        #pragma unroll
        for (int i = 0; i < 2; ++i) {
            int m = mA + i * 32;
            int row = rowBase + m;
            As[kA][m] = (row < M) ? A[(size_t)row * K + k0 + kA] : 0.f;
        }
        #pragma unroll
        for (int i = 0; i < 2; ++i) {
            int k = kB + i * 4;
            Bs[k][nB] = B[(size_t)(k0 + k) * N + colBase + nB];
        }
        __syncthreads();
        #pragma unroll
        for (int kk = 0; kk < BK; ++kk) {
            float4 av = *reinterpret_cast<float4*>(&As[kk][ty << 2]);
            float4 bv = *reinterpret_cast<float4*>(&Bs[kk][tx << 2]);
            float a[4] = {av.x, av.y, av.z, av.w};
            float b[4] = {bv.x, bv.y, bv.z, bv.w};
            #pragma unroll
            for (int mi = 0; mi < 4; ++mi)
                #pragma unroll
                for (int ni = 0; ni < 4; ++ni)
                    acc[mi][ni] += a[mi] * b[ni];
        }
        __syncthreads();
    }
    float w3s[4];
    #pragma unroll
    for (int ni = 0; ni < 4; ++ni) w3s[ni] = W3[colBase + (tx << 2) + ni] * alpha3;
    float rs[4];
    #pragma unroll
    for (int mi = 0; mi < 4; ++mi) {
        float s = 0.f;
        #pragma unroll
        for (int ni = 0; ni < 4; ++ni) {
            int col = colBase + (tx << 2) + ni;
            float x = alpha * acc[mi][ni] + 0.1f * bias[col];
            float v = x / (1.f + expf(-x));
            s += v * w3s[ni];
        }
        rs[mi] = s;
    }
    #pragma unroll
    for (int mi = 0; mi < 4; ++mi) {
        #pragma unroll
        for (int off = 1; off < 16; off <<= 1)
            rs[mi] += __shfl_xor(rs[mi], off, 64);
    }
    if (tx == 0) {
        #pragma unroll
        for (int mi = 0; mi < 4; ++mi) {
            int row = rowBase + (ty << 2) + mi;
            if (row < M) atomicAdd(&outacc[row], rs[mi]);
        }
    }
}

__global__ void finalize_kernel(float* __restrict__ out, const int* __restrict__ Z,
                                const float* __restrict__ b3, int natoms)
{
    int a = blockIdx.x * 256 + threadIdx.x;
    if (a >= natoms) return;
    float v = out[a] + 0.1f * b3[0];
    out[a] = (Z[a] > 0) ? v : 0.f;
}

extern "C" void kernel_launch(void* const* d_in, const int* in_sizes, int n_in,
                              void* d_out, int out_size, void* d_ws, size_t ws_size,
                              hipStream_t stream)
{
    const float* R       = (const float*)d_in[0];
    const int*   Z       = (const int*)  d_in[1];
    const int*   nbr     = (const int*)  d_in[2];
    // d_in[3] = box (unused)
    const float* offsets = (const float*)d_in[4];
    const float* emb     = (const float*)d_in[5];
    const float* W1      = (const float*)d_in[6];
    const float* b1      = (const float*)d_in[7];
    const float* W2      = (const float*)d_in[8];
    const float* b2      = (const float*)d_in[9];
    const float* W3      = (const float*)d_in[10];
    const float* b3      = (const float*)d_in[11];

    int natoms = in_sizes[0] / 3;
    int npairs = in_sizes[2] / 2;

    int*   counts = (int*)d_ws;
    int*   offs   = counts + natoms;
    int*   cursor = offs + natoms;
    int*   sorted = cursor + natoms;
    float* feats  = (float*)(sorted + npairs);
    float* h1     = feats + (size_t)natoms * NFEAT;

    hipMemsetAsync(counts, 0, (size_t)natoms * sizeof(int), stream);
    hipMemsetAsync(d_out, 0, (size_t)natoms * sizeof(float), stream);

    int pgrid = (npairs + 255) / 256;
    hist_kernel<<<dim3(pgrid), 256, 0, stream>>>(R, nbr, offsets, counts, npairs);
    scan_kernel<<<dim3(1), 1024, 0, stream>>>(counts, offs, cursor, natoms);
    scatter_kernel<<<dim3(pgrid), 256, 0, stream>>>(R, nbr, offsets, cursor, sorted, npairs);
    accum_feat_kernel<<<dim3(natoms), DBLK, 0, stream>>>(
        R, Z, nbr, offsets, emb, sorted, offs, counts, feats, npairs);

    dim3 grid1((natoms + BM - 1) / BM, UNITS / BN);
    float a1 = 1.0f / sqrtf((float)NFEAT);
    gemm_swish<<<grid1, 256, 0, stream>>>(feats, W1, b1, h1, natoms, UNITS, NFEAT, a1);

    float a2 = 1.0f / sqrtf((float)UNITS);
    gemm_swish_w3<<<grid1, 256, 0, stream>>>(h1, W2, b2, W3, (float*)d_out,
                                             natoms, UNITS, UNITS, a2, a2);

    finalize_kernel<<<dim3((natoms + 255) / 256), 256, 0, stream>>>(
        (float*)d_out, Z, b3, natoms);
}

// Round 3
// 307.483 us; speedup vs baseline: 5.2622x; 1.7052x over previous
//
#include <hip/hip_runtime.h>
#include <hip/hip_bf16.h>
#include <cmath>

#define NSP 119
#define UNITS 512
#define NFEAT 360
#define KP1 384          // NFEAT padded to multiple of 32
#define DBLK 128

typedef __attribute__((ext_vector_type(8))) short short8;
typedef __attribute__((ext_vector_type(4))) float floatx4;

// ---------- constant index tables ----------
__constant__ int T2I[15] = {0,1,1,2,2,2,3,3,3,3,4,4,4,4,4};
__constant__ int T2J[15] = {0,0,1,0,1,2,0,1,2,3,0,1,2,3,4};
__constant__ int T3A[35] = {0, 1,1,1, 2,2,2,2,2,2, 3,3,3,3,3,3,3,3,3,3, 4,4,4,4,4,4,4,4,4,4,4,4,4,4,4};
__constant__ int T3B[35] = {0, 0,1,1, 0,1,1,2,2,2, 0,1,1,2,2,2,3,3,3,3, 0,1,1,2,2,2,3,3,3,3,4,4,4,4,4};
__constant__ int T3C[35] = {0, 0,0,1, 0,0,1,0,1,2, 0,0,1,0,1,2,0,1,2,3, 0,0,1,0,1,2,0,1,2,3,0,1,2,3,4};
__constant__ int P2X[6] = {0,1,1,2,2,2};
__constant__ int P2Y[6] = {0,0,1,0,1,2};
__constant__ int P3X[10] = {0,1,1,1,2,2,2,2,2,2};
__constant__ int P3Y[10] = {0,0,1,1,0,1,1,2,2,2};
__constant__ int P3Z[10] = {0,0,0,1,0,0,1,0,1,2};

// ---------- async 16B global->LDS ----------
static __device__ __forceinline__ void load16_to_lds(const void* g, void* l) {
    __builtin_amdgcn_global_load_lds(
        (const __attribute__((address_space(1))) void*)g,
        (__attribute__((address_space(3))) void*)l, 16, 0, 0);
}

// ---------- phase 1a: histogram of in-cutoff pairs per center atom ----------
__global__ __launch_bounds__(256) void hist_kernel(
    const float* __restrict__ R, const int* __restrict__ nbr,
    const float* __restrict__ offsets, int* __restrict__ counts, int npairs)
{
    int p = blockIdx.x * 256 + threadIdx.x;
    if (p >= npairs) return;
    int i = nbr[p];
    int j = nbr[npairs + p];
    float dx = R[3*j]   - R[3*i]   + offsets[3*p];
    float dy = R[3*j+1] - R[3*i+1] + offsets[3*p+1];
    float dz = R[3*j+2] - R[3*i+2] + offsets[3*p+2];
    float dr2 = dx*dx + dy*dy + dz*dz;
    if (dr2 < 36.0f) atomicAdd(&counts[i], 1);
}

// ---------- phase 1b: exclusive scan (single block) ----------
__global__ __launch_bounds__(1024) void scan_kernel(
    const int* __restrict__ counts, int* __restrict__ offs,
    int* __restrict__ cursor, int n)
{
    __shared__ int tile[1024];
    __shared__ int carry;
    int tid = threadIdx.x;
    if (tid == 0) carry = 0;
    __syncthreads();
    for (int base = 0; base < n; base += 1024) {
        int idx = base + tid;
        int v = (idx < n) ? counts[idx] : 0;
        tile[tid] = v;
        __syncthreads();
        for (int off = 1; off < 1024; off <<= 1) {
            int t = (tid >= off) ? tile[tid - off] : 0;
            __syncthreads();
            tile[tid] += t;
            __syncthreads();
        }
        int excl = carry + tile[tid] - v;
        if (idx < n) { offs[idx] = excl; cursor[idx] = excl; }
        __syncthreads();
        if (tid == 1023) carry += tile[1023];
        __syncthreads();
    }
}

// ---------- phase 1c: scatter pair indices into per-atom segments ----------
__global__ __launch_bounds__(256) void scatter_kernel(
    const float* __restrict__ R, const int* __restrict__ nbr,
    const float* __restrict__ offsets, int* __restrict__ cursor,
    int* __restrict__ sorted, int npairs)
{
    int p = blockIdx.x * 256 + threadIdx.x;
    if (p >= npairs) return;
    int i = nbr[p];
    int j = nbr[npairs + p];
    float dx = R[3*j]   - R[3*i]   + offsets[3*p];
    float dy = R[3*j+1] - R[3*i+1] + offsets[3*p+1];
    float dz = R[3*j+2] - R[3*i+2] + offsets[3*p+2];
    float dr2 = dx*dx + dy*dy + dz*dz;
    if (dr2 < 36.0f) {
        int pos = atomicAdd(&cursor[i], 1);
        sorted[pos] = p;
    }
}

// ---------- weight transpose+pad to bf16: Wt[n*Kp+k] = W[k*N+n] ----------
__global__ __launch_bounds__(256) void prep_w_t(
    const float* __restrict__ W, __hip_bfloat16* __restrict__ Wt,
    int K, int N, int Kp)
{
    int idx = blockIdx.x * 256 + threadIdx.x;
    if (idx >= N * Kp) return;
    int n = idx / Kp, k = idx % Kp;
    float v = (k < K) ? W[(size_t)k * N + n] : 0.f;
    Wt[idx] = __float2bfloat16(v);
}

// ---------- phase 2: per-atom moments + contractions -> 360 bf16 features ----------
__global__ __launch_bounds__(DBLK) void accum_feat_kernel(
    const float* __restrict__ R, const int* __restrict__ Z,
    const int* __restrict__ nbr, const float* __restrict__ offsets,
    const float* __restrict__ emb, const int* __restrict__ sorted,
    const int* __restrict__ offs, const int* __restrict__ counts,
    __hip_bfloat16* __restrict__ feats, int npairs)
{
    int a = blockIdx.x;
    int tid = threadIdx.x;
    __shared__ float stage[DBLK][8];   // per-pair rad[5] | dn[3]
    __shared__ float raw[100];         // unique sym moments
    __shared__ float F[200];           // expanded full moments

    int start = offs[a];
    int cnt = counts[a];
    float Ri0 = R[3*a], Ri1 = R[3*a+1], Ri2 = R[3*a+2];
    int Zi = Z[a];

    int cr = 0, nf = 0, i0 = 0, i1 = 0, i2 = 0;
    if (tid < 5)        { cr = tid; nf = 0; }
    else if (tid < 20)  { int c = tid - 5;  cr = c / 3;  nf = 1; i0 = c % 3; }
    else if (tid < 50)  { int c = tid - 20; cr = c / 6;  int k = c % 6;  nf = 2; i0 = P2X[k]; i1 = P2Y[k]; }
    else if (tid < 100) { int c = tid - 50; cr = c / 10; int k = c % 10; nf = 3; i0 = P3X[k]; i1 = P3Y[k]; i2 = P3Z[k]; }

    float acc = 0.f;
    for (int base = 0; base < cnt; base += DBLK) {
        int m = min(DBLK, cnt - base);
        if (tid < m) {
            int p = sorted[start + base + tid];
            int j = nbr[npairs + p];
            float dx = R[3*j]   - Ri0 + offsets[3*p];
            float dy = R[3*j+1] - Ri1 + offsets[3*p+1];
            float dz = R[3*j+2] - Ri2 + offsets[3*p+2];
            float dr = sqrtf(dx*dx + dy*dy + dz*dz);
            float inv = 1.0f / (dr + 1e-5f);
            float cutoff = 0.5f * (cosf(0.523598775598299f * dr) + 1.0f);
            const float betta = 49.0f / 36.0f;
            const float rad_norm = expf(0.75f * logf(2.0f * betta / 3.14159265358979f));
            float basis[7];
            #pragma unroll
            for (int b = 0; b < 7; ++b) {
                float sh = 0.5f + b * (5.5f / 6.0f);
                float d = dr - sh;
                basis[b] = rad_norm * expf(-betta * d * d);
            }
            const float* e = emb + ((size_t)Z[j] * NSP + Zi) * 35;
            const float EMBN = 0.377964473009227f;
            #pragma unroll
            for (int r = 0; r < 5; ++r) {
                float s = 0.f;
                #pragma unroll
                for (int b = 0; b < 7; ++b) s += e[r*7 + b] * basis[b];
                stage[tid][r] = EMBN * s * cutoff;
            }
            stage[tid][5] = dx * inv;
            stage[tid][6] = dy * inv;
            stage[tid][7] = dz * inv;
        }
        __syncthreads();
        if (tid < 100) {
            for (int q = 0; q < m; ++q) {
                const float* s = stage[q];
                float v = s[cr];
                if (nf > 0) v *= s[5 + i0];
                if (nf > 1) v *= s[5 + i1];
                if (nf > 2) v *= s[5 + i2];
                acc += v;
            }
        }
        __syncthreads();
    }
    if (tid < 100) raw[tid] = acc;
    __syncthreads();

    for (int idx = tid; idx < 200; idx += DBLK) {
        float v;
        if (idx < 20) {
            v = raw[idx];
        } else if (idx < 65) {
            int rel = idx - 20, r = rel / 9, q = rel % 9, x = q / 3, y = q % 3;
            int hi = max(x, y), lo = min(x, y);
            v = raw[20 + r*6 + hi*(hi+1)/2 + lo];
        } else {
            int rel = idx - 65, r = rel / 27, q = rel % 27;
            int x = q / 9, y = (q / 3) % 3, z = q % 3;
            int A = max(x, max(y, z)), C = min(x, min(y, z)), B = x + y + z - A - C;
            v = raw[50 + r*10 + A*(A+1)*(A+2)/6 + B*(B+1)/2 + C];
        }
        F[idx] = v;
    }
    __syncthreads();

    const float* M0 = F;
    const float* M1 = F + 5;
    const float* M2 = F + 20;
    const float* M3 = F + 65;
    __hip_bfloat16* out = feats + (size_t)a * KP1;
    for (int f = tid; f < NFEAT; f += DBLK) {
        float v = 0.f;
        if (f < 5) {
            v = M0[f];
        } else if (f < 20) {
            int p = f - 5, r = T2I[p], s = T2J[p];
            for (int x = 0; x < 3; ++x) v += M1[r*3+x] * M1[s*3+x];
        } else if (f < 35) {
            int p = f - 20, r = T2I[p], s = T2J[p];
            for (int q = 0; q < 9; ++q) v += M2[r*9+q] * M2[s*9+q];
        } else if (f < 50) {
            int p = f - 35, r = T2I[p], s = T2J[p];
            for (int q = 0; q < 27; ++q) v += M3[r*27+q] * M3[s*27+q];
        } else if (f < 85) {
            int q = f - 50, r = T3A[q], s = T3B[q], t = T3C[q];
            for (int x = 0; x < 3; ++x)
                for (int y = 0; y < 3; ++y)
                    for (int z = 0; z < 3; ++z)
                        v += M2[r*9+x*3+y] * M2[s*9+x*3+z] * M2[t*9+y*3+z];
        } else if (f < 160) {
            int q = f - 85, p = q / 5, t = q % 5, r = T2I[p], s = T2J[p];
            for (int x = 0; x < 3; ++x)
                for (int y = 0; y < 3; ++y)
                    v += M1[r*3+x] * M1[s*3+y] * M2[t*9+x*3+y];
        } else if (f < 235) {
            int q = f - 160, p = q / 5, t = q % 5, r = T2I[p], s = T2J[p];
            for (int z = 0; z < 3; ++z)
                for (int w = 0; w < 3; ++w) {
                    float bs = 0.f;
                    for (int x = 0; x < 3; ++x)
                        for (int y = 0; y < 3; ++y)
                            bs += M3[r*27+x*9+y*3+z] * M3[s*27+x*9+y*3+w];
                    v += bs * M2[t*9+z*3+w];
                }
        } else {
            int q = f - 235, r = q / 25, s = (q / 5) % 5, t = q % 5;
            for (int z = 0; z < 3; ++z) {
                float bs = 0.f;
                for (int x = 0; x < 3; ++x)
                    for (int y = 0; y < 3; ++y)
                        bs += M3[r*27+x*9+y*3+z] * M2[s*9+x*3+y];
                v += bs * M1[t*3+z];
            }
        }
        out[f] = __float2bfloat16(v);
    }
}

// ---------- bf16 MFMA GEMM, 128x128 tile, BK=32, swish epilogue ----------
// A: [Mpad x Kp] bf16 row-major. Bt: [512 x Kp] bf16 (N-major = B^T).
// fuse==0: C[row*512+col] = bf16(swish(alpha*acc + 0.1*bias[col]))
// fuse==1: atomicAdd(outacc[row], sum_col swish(...)*w3[col]*a3), row<M
__global__ __launch_bounds__(256) void gemm_mfma_swish(
    const __hip_bfloat16* __restrict__ A, const __hip_bfloat16* __restrict__ Bt,
    const float* __restrict__ bias, __hip_bfloat16* __restrict__ C,
    const float* __restrict__ w3, float* __restrict__ outacc,
    int Kp, int M, float alpha, float a3, int fuse)
{
    __shared__ __hip_bfloat16 As[128 * 32];
    __shared__ __hip_bfloat16 Bs[128 * 32];
    int tid = threadIdx.x;
    int wave = tid >> 6, lane = tid & 63;
    int quad = lane >> 4, l16 = lane & 15;
    int wm = wave >> 1, wn = wave & 1;
    int rowBase = blockIdx.x * 128;
    int colBase = blockIdx.y * 128;

    floatx4 acc[4][4] = {};

    const __hip_bfloat16* Ag = A + (size_t)rowBase * Kp;
    const __hip_bfloat16* Bg = Bt + (size_t)colBase * Kp;
    int lrow = tid >> 2;
    int lcol = (tid & 3) * 8;

    for (int k0 = 0; k0 < Kp; k0 += 32) {
        #pragma unroll
        for (int i = 0; i < 2; ++i) {
            const __hip_bfloat16* ga = Ag + (size_t)(i*64 + lrow) * Kp + (k0 + lcol);
            load16_to_lds(ga, (char*)As + i*4096 + wave*1024);
            const __hip_bfloat16* gb = Bg + (size_t)(i*64 + lrow) * Kp + (k0 + lcol);
            load16_to_lds(gb, (char*)Bs + i*4096 + wave*1024);
        }
        __syncthreads();
        short8 af[4], bf[4];
        #pragma unroll
        for (int t = 0; t < 4; ++t) {
            af[t] = *(const short8*)(As + (wm*64 + t*16 + l16)*32 + quad*8);
            bf[t] = *(const short8*)(Bs + (wn*64 + t*16 + l16)*32 + quad*8);
        }
        #pragma unroll
        for (int tm = 0; tm < 4; ++tm)
            #pragma unroll
            for (int tn = 0; tn < 4; ++tn)
                acc[tm][tn] = __builtin_amdgcn_mfma_f32_16x16x32_bf16(
                    af[tm], bf[tn], acc[tm][tn], 0, 0, 0);
        __syncthreads();
    }

    if (!fuse) {
        #pragma unroll
        for (int tn = 0; tn < 4; ++tn) {
            int col = colBase + wn*64 + tn*16 + l16;
            float bc = 0.1f * bias[col];
            #pragma unroll
            for (int tm = 0; tm < 4; ++tm) {
                int row0 = rowBase + wm*64 + tm*16 + quad*4;
                #pragma unroll
                for (int r = 0; r < 4; ++r) {
                    float x = alpha * acc[tm][tn][r] + bc;
                    float v = x / (1.f + expf(-x));
                    C[(size_t)(row0 + r) * UNITS + col] = __float2bfloat16(v);
                }
            }
        }
    } else {
        float rowsum[4][4] = {};
        #pragma unroll
        for (int tn = 0; tn < 4; ++tn) {
            int col = colBase + wn*64 + tn*16 + l16;
            float bc = 0.1f * bias[col];
            float w3c = w3[col] * a3;
            #pragma unroll
            for (int tm = 0; tm < 4; ++tm)
                #pragma unroll
                for (int r = 0; r < 4; ++r) {
                    float x = alpha * acc[tm][tn][r] + bc;
                    float v = x / (1.f + expf(-x));
                    rowsum[tm][r] += v * w3c;
                }
        }
        #pragma unroll
        for (int tm = 0; tm < 4; ++tm)
            #pragma unroll
            for (int r = 0; r < 4; ++r) {
                float s = rowsum[tm][r];
                s += __shfl_xor(s, 1, 64);
                s += __shfl_xor(s, 2, 64);
                s += __shfl_xor(s, 4, 64);
                s += __shfl_xor(s, 8, 64);
                rowsum[tm][r] = s;
            }
        if (l16 == 0) {
            #pragma unroll
            for (int tm = 0; tm < 4; ++tm) {
                int row0 = rowBase + wm*64 + tm*16 + quad*4;
                #pragma unroll
                for (int r = 0; r < 4; ++r)
                    if (row0 + r < M) atomicAdd(&outacc[row0 + r], rowsum[tm][r]);
            }
        }
    }
}

__global__ void finalize_kernel(float* __restrict__ out, const int* __restrict__ Z,
                                const float* __restrict__ b3, int natoms)
{
    int a = blockIdx.x * 256 + threadIdx.x;
    if (a >= natoms) return;
    float v = out[a] + 0.1f * b3[0];
    out[a] = (Z[a] > 0) ? v : 0.f;
}

static inline size_t align_up(size_t x, size_t a) { return (x + a - 1) & ~(a - 1); }

extern "C" void kernel_launch(void* const* d_in, const int* in_sizes, int n_in,
                              void* d_out, int out_size, void* d_ws, size_t ws_size,
                              hipStream_t stream)
{
    const float* R       = (const float*)d_in[0];
    const int*   Z       = (const int*)  d_in[1];
    const int*   nbr     = (const int*)  d_in[2];
    const float* offsets = (const float*)d_in[4];
    const float* emb     = (const float*)d_in[5];
    const float* W1      = (const float*)d_in[6];
    const float* b1      = (const float*)d_in[7];
    const float* W2      = (const float*)d_in[8];
    const float* b2      = (const float*)d_in[9];
    const float* W3      = (const float*)d_in[10];
    const float* b3      = (const float*)d_in[11];

    int natoms = in_sizes[0] / 3;
    int npairs = in_sizes[2] / 2;
    int Mpad = ((natoms + 127) / 128) * 128;

    char* ws = (char*)d_ws;
    size_t off = 0;
    int* counts = (int*)(ws + off); off = align_up(off + natoms*4, 256);
    int* offs   = (int*)(ws + off); off = align_up(off + natoms*4, 256);
    int* cursor = (int*)(ws + off); off = align_up(off + natoms*4, 256);
    int* sorted = (int*)(ws + off); off = align_up(off + (size_t)npairs*4, 256);
    __hip_bfloat16* W1t   = (__hip_bfloat16*)(ws + off); off = align_up(off + (size_t)UNITS*KP1*2, 256);
    __hip_bfloat16* W2t   = (__hip_bfloat16*)(ws + off); off = align_up(off + (size_t)UNITS*UNITS*2, 256);
    __hip_bfloat16* feats = (__hip_bfloat16*)(ws + off); off = align_up(off + (size_t)Mpad*KP1*2, 256);
    __hip_bfloat16* h1    = (__hip_bfloat16*)(ws + off); off = align_up(off + (size_t)Mpad*UNITS*2, 256);

    hipMemsetAsync(counts, 0, (size_t)natoms * sizeof(int), stream);
    hipMemsetAsync(d_out, 0, (size_t)natoms * sizeof(float), stream);

    int pgrid = (npairs + 255) / 256;
    hist_kernel<<<dim3(pgrid), 256, 0, stream>>>(R, nbr, offsets, counts, npairs);
    scan_kernel<<<dim3(1), 1024, 0, stream>>>(counts, offs, cursor, natoms);
    scatter_kernel<<<dim3(pgrid), 256, 0, stream>>>(R, nbr, offsets, cursor, sorted, npairs);

    prep_w_t<<<dim3((UNITS*KP1 + 255)/256), 256, 0, stream>>>(W1, W1t, NFEAT, UNITS, KP1);
    prep_w_t<<<dim3((UNITS*UNITS + 255)/256), 256, 0, stream>>>(W2, W2t, UNITS, UNITS, UNITS);

    accum_feat_kernel<<<dim3(natoms), DBLK, 0, stream>>>(
        R, Z, nbr, offsets, emb, sorted, offs, counts, feats, npairs);

    float a1 = 1.0f / sqrtf((float)NFEAT);
    float a2 = 1.0f / sqrtf((float)UNITS);
    dim3 ggrid(Mpad / 128, UNITS / 128);
    gemm_mfma_swish<<<ggrid, 256, 0, stream>>>(
        feats, W1t, b1, h1, nullptr, nullptr, KP1, natoms, a1, 0.f, 0);
    gemm_mfma_swish<<<ggrid, 256, 0, stream>>>(
        h1, W2t, b2, nullptr, W3, (float*)d_out, UNITS, natoms, a2, a2, 1);

    finalize_kernel<<<dim3((natoms + 255) / 256), 256, 0, stream>>>(
        (float*)d_out, Z, b3, natoms);
}

// Round 4
// 283.162 us; speedup vs baseline: 5.7142x; 1.0859x over previous
//
#include <hip/hip_runtime.h>
#include <hip/hip_bf16.h>
#include <cmath>

#define NSP 119
#define UNITS 512
#define NFEAT 360
#define KP1 384          // NFEAT padded to multiple of 32

typedef __attribute__((ext_vector_type(8))) short short8;
typedef __attribute__((ext_vector_type(4))) float floatx4;

// ---------- constant index tables ----------
__constant__ int T2I[15] = {0,1,1,2,2,2,3,3,3,3,4,4,4,4,4};
__constant__ int T2J[15] = {0,0,1,0,1,2,0,1,2,3,0,1,2,3,4};
__constant__ int T3A[35] = {0, 1,1,1, 2,2,2,2,2,2, 3,3,3,3,3,3,3,3,3,3, 4,4,4,4,4,4,4,4,4,4,4,4,4,4,4};
__constant__ int T3B[35] = {0, 0,1,1, 0,1,1,2,2,2, 0,1,1,2,2,2,3,3,3,3, 0,1,1,2,2,2,3,3,3,3,4,4,4,4,4};
__constant__ int T3C[35] = {0, 0,0,1, 0,0,1,0,1,2, 0,0,1,0,1,2,0,1,2,3, 0,0,1,0,1,2,0,1,2,3,0,1,2,3,4};
__constant__ int P2X[6] = {0,1,1,2,2,2};
__constant__ int P2Y[6] = {0,0,1,0,1,2};
__constant__ int P3X[10] = {0,1,1,1,2,2,2,2,2,2};
__constant__ int P3Y[10] = {0,0,1,1,0,1,1,2,2,2};
__constant__ int P3Z[10] = {0,0,0,1,0,0,1,0,1,2};

// ---------- async 16B global->LDS ----------
static __device__ __forceinline__ void load16_to_lds(const void* g, void* l) {
    __builtin_amdgcn_global_load_lds(
        (const __attribute__((address_space(1))) void*)g,
        (__attribute__((address_space(3))) void*)l, 16, 0, 0);
}

// ---------- phase 1a: histogram of in-cutoff pairs per center atom ----------
__global__ __launch_bounds__(256) void hist_kernel(
    const float* __restrict__ R, const int* __restrict__ nbr,
    const float* __restrict__ offsets, int* __restrict__ counts, int npairs)
{
    int p = blockIdx.x * 256 + threadIdx.x;
    if (p >= npairs) return;
    int i = nbr[p];
    int j = nbr[npairs + p];
    float dx = R[3*j]   - R[3*i]   + offsets[3*p];
    float dy = R[3*j+1] - R[3*i+1] + offsets[3*p+1];
    float dz = R[3*j+2] - R[3*i+2] + offsets[3*p+2];
    float dr2 = dx*dx + dy*dy + dz*dz;
    if (dr2 < 36.0f) atomicAdd(&counts[i], 1);
}

// ---------- phase 1b: exclusive scan, single block, 32 items/thread ----------
__global__ __launch_bounds__(1024) void scan_kernel(
    const int* __restrict__ counts, int* __restrict__ offs,
    int* __restrict__ cursor, int n)
{
    int tid = threadIdx.x;
    int lane = tid & 63, wid = tid >> 6;
    int beg = tid * 32;
    int local[32];
    int s = 0;
    #pragma unroll
    for (int k = 0; k < 32; ++k) {
        int idx = beg + k;
        int v = (idx < n) ? counts[idx] : 0;
        local[k] = s;
        s += v;
    }
    // inclusive wave scan of thread sums
    int incl = s;
    #pragma unroll
    for (int off = 1; off < 64; off <<= 1) {
        int t = __shfl_up(incl, off, 64);
        if (lane >= off) incl += t;
    }
    __shared__ int wsum[16];
    if (lane == 63) wsum[wid] = incl;
    __syncthreads();
    if (tid < 16) {
        int v = wsum[tid];
        int inc2 = v;
        #pragma unroll
        for (int off = 1; off < 16; off <<= 1) {
            int t = __shfl_up(inc2, off, 64);
            if (tid >= off) inc2 += t;
        }
        wsum[tid] = inc2 - v; // exclusive wave base
    }
    __syncthreads();
    int base = wsum[wid] + (incl - s);
    #pragma unroll
    for (int k = 0; k < 32; ++k) {
        int idx = beg + k;
        if (idx < n) { int v = base + local[k]; offs[idx] = v; cursor[idx] = v; }
    }
}

// ---------- phase 1c: scatter pair indices into per-atom segments ----------
__global__ __launch_bounds__(256) void scatter_kernel(
    const float* __restrict__ R, const int* __restrict__ nbr,
    const float* __restrict__ offsets, int* __restrict__ cursor,
    int* __restrict__ sorted, int npairs)
{
    int p = blockIdx.x * 256 + threadIdx.x;
    if (p >= npairs) return;
    int i = nbr[p];
    int j = nbr[npairs + p];
    float dx = R[3*j]   - R[3*i]   + offsets[3*p];
    float dy = R[3*j+1] - R[3*i+1] + offsets[3*p+1];
    float dz = R[3*j+2] - R[3*i+2] + offsets[3*p+2];
    float dr2 = dx*dx + dy*dy + dz*dz;
    if (dr2 < 36.0f) {
        int pos = atomicAdd(&cursor[i], 1);
        sorted[pos] = p;
    }
}

// ---------- phase 1d: per-pair rad[5]+dn[3] records, fully pair-parallel ----------
__global__ __launch_bounds__(256) void pair_compute_kernel(
    const float* __restrict__ R, const int* __restrict__ Z,
    const int* __restrict__ nbr, const float* __restrict__ offsets,
    const float* __restrict__ emb, const int* __restrict__ sorted,
    const int* __restrict__ ntotal_ptr, float* __restrict__ pairdata, int npairs)
{
    int pos = blockIdx.x * 256 + threadIdx.x;
    if (pos >= *ntotal_ptr) return;
    int p = sorted[pos];
    int i = nbr[p], j = nbr[npairs + p];
    float dx = R[3*j]   - R[3*i]   + offsets[3*p];
    float dy = R[3*j+1] - R[3*i+1] + offsets[3*p+1];
    float dz = R[3*j+2] - R[3*i+2] + offsets[3*p+2];
    float dr = sqrtf(dx*dx + dy*dy + dz*dz);
    float inv = 1.0f / (dr + 1e-5f);
    float cutoff = 0.5f * (cosf(0.523598775598299f * dr) + 1.0f); // pi/R_MAX
    const float betta = 49.0f / 36.0f;
    const float rad_norm = expf(0.75f * logf(2.0f * betta / 3.14159265358979f));
    float basis[7];
    #pragma unroll
    for (int b = 0; b < 7; ++b) {
        float sh = 0.5f + b * (5.5f / 6.0f);
        float d = dr - sh;
        basis[b] = rad_norm * expf(-betta * d * d);
    }
    const float* e = emb + ((size_t)Z[j] * NSP + Z[i]) * 35;
    const float EMBN = 0.377964473009227f; // 1/sqrt(7)
    float rec[8];
    #pragma unroll
    for (int r = 0; r < 5; ++r) {
        float s = 0.f;
        #pragma unroll
        for (int b = 0; b < 7; ++b) s += e[r*7 + b] * basis[b];
        rec[r] = EMBN * s * cutoff;
    }
    rec[5] = dx * inv; rec[6] = dy * inv; rec[7] = dz * inv;
    float4* out = (float4*)(pairdata + (size_t)pos * 8);
    out[0] = make_float4(rec[0], rec[1], rec[2], rec[3]);
    out[1] = make_float4(rec[4], rec[5], rec[6], rec[7]);
}

// ---------- phase 2: one wave per atom: moments + contractions -> 360 bf16 feats ----------
#define SREC 12   // stage record stride (floats); [0..4]=rad, [5..7]=dn, [8]=1.0
__global__ __launch_bounds__(256) void moment_feat_kernel(
    const float* __restrict__ pairdata, const int* __restrict__ offs,
    const int* __restrict__ counts, __hip_bfloat16* __restrict__ feats, int natoms)
{
    int wv = threadIdx.x >> 6, lane = threadIdx.x & 63;
    int a = blockIdx.x * 4 + wv;
    __shared__ float stage[4][64][SREC];
    __shared__ float F[4][200];
    __shared__ float B2[4][135];
    __shared__ float A3[4][75];
    if (a >= natoms) return;   // wave-uniform; no __syncthreads in this kernel

    int start = offs[a], cnt = counts[a];

    // component ownership: lane -> comp c0=lane; c1=64+lane (valid if lane<36)
    int cr0, f00 = 8, f01 = 8, f02 = 8;
    if (lane < 5)       { cr0 = lane; }
    else if (lane < 20) { int c = lane - 5;  cr0 = c / 3; f00 = 5 + c % 3; }
    else if (lane < 50) { int c = lane - 20; cr0 = c / 6; int k = c % 6;
                          f00 = 5 + P2X[k]; f01 = 5 + P2Y[k]; }
    else                { int c = lane - 50; cr0 = c / 10; int k = c % 10;
                          f00 = 5 + P3X[k]; f01 = 5 + P3Y[k]; f02 = 5 + P3Z[k]; }
    int cr1 = 8, f10 = 8, f11 = 8, f12 = 8;
    if (lane < 36) { int c = 14 + lane; cr1 = c / 10; int k = c % 10;
                     f10 = 5 + P3X[k]; f11 = 5 + P3Y[k]; f12 = 5 + P3Z[k]; }

    float acc0 = 0.f, acc1 = 0.f;
    for (int base = 0; base < cnt; base += 64) {
        int m = min(64, cnt - base);
        if (lane < m) {
            const float4* pd = (const float4*)(pairdata + (size_t)(start + base + lane) * 8);
            float4 u = pd[0], v = pd[1];
            float* st = stage[wv][lane];
            ((float4*)st)[0] = u;
            ((float4*)st)[1] = v;
            st[8] = 1.0f;
        }
        __builtin_amdgcn_wave_barrier();
        for (int q = 0; q < m; ++q) {
            const float* s = stage[wv][q];
            acc0 += s[cr0] * s[f00] * s[f01] * s[f02];
            acc1 += s[cr1] * s[f10] * s[f11] * s[f12];
        }
        __builtin_amdgcn_wave_barrier();
    }
    // raw[100] overlays the stage region (done with it)
    float* raw = &stage[wv][0][0];
    __builtin_amdgcn_wave_barrier();
    raw[lane] = acc0;
    if (lane < 36) raw[64 + lane] = acc1;
    __builtin_amdgcn_wave_barrier();

    // expand unique sym components -> full tensors F[200]
    #pragma unroll
    for (int it = 0; it < 4; ++it) {
        int idx = lane + it * 64;
        if (idx < 200) {
            float v;
            if (idx < 20) {
                v = raw[idx];
            } else if (idx < 65) {
                int rel = idx - 20, r = rel / 9, q = rel % 9, x = q / 3, y = q % 3;
                int hi = max(x, y), lo = min(x, y);
                v = raw[20 + r*6 + hi*(hi+1)/2 + lo];
            } else {
                int rel = idx - 65, r = rel / 27, q = rel % 27;
                int x = q / 9, y = (q / 3) % 3, z = q % 3;
                int A = max(x, max(y, z)), C = min(x, min(y, z)), B = x + y + z - A - C;
                v = raw[50 + r*10 + A*(A+1)*(A+2)/6 + B*(B+1)/2 + C];
            }
            F[wv][idx] = v;
        }
    }
    __builtin_amdgcn_wave_barrier();

    const float* M0 = F[wv];
    const float* M1 = F[wv] + 5;    // [r*3+x]
    const float* M2 = F[wv] + 20;   // [r*9+x*3+y]
    const float* M3 = F[wv] + 65;   // [r*27+x*9+y*3+z]

    // precompute shared intermediates:
    // B2[p*9+z*3+w] = sum_xy M3[r,x,y,z]*M3[s,x,y,w]  (p->(r,s) lower-tri)
    // A3[(r*5+s)*3+z] = sum_xy M3[r,x,y,z]*M2[s,x,y]
    #pragma unroll
    for (int it = 0; it < 4; ++it) {
        int idx = lane + it * 64;
        if (idx < 135) {
            int p = idx / 9, zw = idx % 9, z = zw / 3, w_ = zw % 3;
            int r = T2I[p], s = T2J[p];
            float b = 0.f;
            for (int x = 0; x < 3; ++x)
                for (int y = 0; y < 3; ++y)
                    b += M3[r*27 + x*9 + y*3 + z] * M3[s*27 + x*9 + y*3 + w_];
            B2[wv][idx] = b;
        } else if (idx < 210) {
            int e = idx - 135;
            int rs = e / 3, z = e % 3;
            int r = rs / 5, s = rs % 5;
            float av = 0.f;
            for (int x = 0; x < 3; ++x)
                for (int y = 0; y < 3; ++y)
                    av += M3[r*27 + x*9 + y*3 + z] * M2[s*9 + x*3 + y];
            A3[wv][e] = av;
        }
    }
    __builtin_amdgcn_wave_barrier();

    __hip_bfloat16* out = feats + (size_t)a * KP1;
    for (int f = lane; f < NFEAT; f += 64) {
        float v = 0.f;
        if (f < 5) {
            v = M0[f];
        } else if (f < 20) {                 // c1
            int p = f - 5, r = T2I[p], s = T2J[p];
            for (int x = 0; x < 3; ++x) v += M1[r*3+x] * M1[s*3+x];
        } else if (f < 35) {                 // c2
            int p = f - 20, r = T2I[p], s = T2J[p];
            for (int q = 0; q < 9; ++q) v += M2[r*9+q] * M2[s*9+q];
        } else if (f < 50) {                 // c3
            int p = f - 35, r = T2I[p], s = T2J[p];
            for (int q = 0; q < 27; ++q) v += M3[r*27+q] * M3[s*27+q];
        } else if (f < 85) {                 // c4
            int q = f - 50, r = T3A[q], s = T3B[q], t = T3C[q];
            for (int x = 0; x < 3; ++x)
                for (int y = 0; y < 3; ++y)
                    for (int z = 0; z < 3; ++z)
                        v += M2[r*9+x*3+y] * M2[s*9+x*3+z] * M2[t*9+y*3+z];
        } else if (f < 160) {                // c5
            int q = f - 85, p = q / 5, t = q % 5, r = T2I[p], s = T2J[p];
            for (int x = 0; x < 3; ++x)
                for (int y = 0; y < 3; ++y)
                    v += M1[r*3+x] * M1[s*3+y] * M2[t*9+x*3+y];
        } else if (f < 235) {                // c6 via B2
            int q = f - 160, p = q / 5, t = q % 5;
            for (int zw = 0; zw < 9; ++zw)
                v += B2[wv][p*9 + zw] * M2[t*9 + zw];
        } else {                             // c7 via A3
            int q = f - 235, r = q / 25, s = (q / 5) % 5, t = q % 5;
            for (int z = 0; z < 3; ++z)
                v += A3[wv][(r*5+s)*3 + z] * M1[t*3 + z];
        }
        out[f] = __float2bfloat16(v);
    }
}

// ---------- weight transpose+pad to bf16: Wt[n*Kp+k] = W[k*N+n] ----------
__global__ __launch_bounds__(256) void prep_w_t(
    const float* __restrict__ W, __hip_bfloat16* __restrict__ Wt,
    int K, int N, int Kp)
{
    int idx = blockIdx.x * 256 + threadIdx.x;
    if (idx >= N * Kp) return;
    int n = idx / Kp, k = idx % Kp;
    float v = (k < K) ? W[(size_t)k * N + n] : 0.f;
    Wt[idx] = __float2bfloat16(v);
}

// ---------- bf16 MFMA GEMM, 128x128 tile, BK=32, swish epilogue ----------
__global__ __launch_bounds__(256) void gemm_mfma_swish(
    const __hip_bfloat16* __restrict__ A, const __hip_bfloat16* __restrict__ Bt,
    const float* __restrict__ bias, __hip_bfloat16* __restrict__ C,
    const float* __restrict__ w3, float* __restrict__ outacc,
    int Kp, int M, float alpha, float a3, int fuse)
{
    __shared__ __hip_bfloat16 As[128 * 32];
    __shared__ __hip_bfloat16 Bs[128 * 32];
    int tid = threadIdx.x;
    int wave = tid >> 6, lane = tid & 63;
    int quad = lane >> 4, l16 = lane & 15;
    int wm = wave >> 1, wn = wave & 1;
    int rowBase = blockIdx.x * 128;
    int colBase = blockIdx.y * 128;

    floatx4 acc[4][4] = {};

    const __hip_bfloat16* Ag = A + (size_t)rowBase * Kp;
    const __hip_bfloat16* Bg = Bt + (size_t)colBase * Kp;
    int lrow = tid >> 2;
    int lcol = (tid & 3) * 8;

    for (int k0 = 0; k0 < Kp; k0 += 32) {
        #pragma unroll
        for (int i = 0; i < 2; ++i) {
            const __hip_bfloat16* ga = Ag + (size_t)(i*64 + lrow) * Kp + (k0 + lcol);
            load16_to_lds(ga, (char*)As + i*4096 + wave*1024);
            const __hip_bfloat16* gb = Bg + (size_t)(i*64 + lrow) * Kp + (k0 + lcol);
            load16_to_lds(gb, (char*)Bs + i*4096 + wave*1024);
        }
        __syncthreads();
        short8 af[4], bf[4];
        #pragma unroll
        for (int t = 0; t < 4; ++t) {
            af[t] = *(const short8*)(As + (wm*64 + t*16 + l16)*32 + quad*8);
            bf[t] = *(const short8*)(Bs + (wn*64 + t*16 + l16)*32 + quad*8);
        }
        #pragma unroll
        for (int tm = 0; tm < 4; ++tm)
            #pragma unroll
            for (int tn = 0; tn < 4; ++tn)
                acc[tm][tn] = __builtin_amdgcn_mfma_f32_16x16x32_bf16(
                    af[tm], bf[tn], acc[tm][tn], 0, 0, 0);
        __syncthreads();
    }

    if (!fuse) {
        #pragma unroll
        for (int tn = 0; tn < 4; ++tn) {
            int col = colBase + wn*64 + tn*16 + l16;
            float bc = 0.1f * bias[col];
            #pragma unroll
            for (int tm = 0; tm < 4; ++tm) {
                int row0 = rowBase + wm*64 + tm*16 + quad*4;
                #pragma unroll
                for (int r = 0; r < 4; ++r) {
                    float x = alpha * acc[tm][tn][r] + bc;
                    float v = x / (1.f + expf(-x));
                    C[(size_t)(row0 + r) * UNITS + col] = __float2bfloat16(v);
                }
            }
        }
    } else {
        float rowsum[4][4] = {};
        #pragma unroll
        for (int tn = 0; tn < 4; ++tn) {
            int col = colBase + wn*64 + tn*16 + l16;
            float bc = 0.1f * bias[col];
            float w3c = w3[col] * a3;
            #pragma unroll
            for (int tm = 0; tm < 4; ++tm)
                #pragma unroll
                for (int r = 0; r < 4; ++r) {
                    float x = alpha * acc[tm][tn][r] + bc;
                    float v = x / (1.f + expf(-x));
                    rowsum[tm][r] += v * w3c;
                }
        }
        #pragma unroll
        for (int tm = 0; tm < 4; ++tm)
            #pragma unroll
            for (int r = 0; r < 4; ++r) {
                float s = rowsum[tm][r];
                s += __shfl_xor(s, 1, 64);
                s += __shfl_xor(s, 2, 64);
                s += __shfl_xor(s, 4, 64);
                s += __shfl_xor(s, 8, 64);
                rowsum[tm][r] = s;
            }
        if (l16 == 0) {
            #pragma unroll
            for (int tm = 0; tm < 4; ++tm) {
                int row0 = rowBase + wm*64 + tm*16 + quad*4;
                #pragma unroll
                for (int r = 0; r < 4; ++r)
                    if (row0 + r < M) atomicAdd(&outacc[row0 + r], rowsum[tm][r]);
            }
        }
    }
}

__global__ void finalize_kernel(float* __restrict__ out, const int* __restrict__ Z,
                                const float* __restrict__ b3, int natoms)
{
    int a = blockIdx.x * 256 + threadIdx.x;
    if (a >= natoms) return;
    float v = out[a] + 0.1f * b3[0];
    out[a] = (Z[a] > 0) ? v : 0.f;
}

static inline size_t align_up(size_t x, size_t a) { return (x + a - 1) & ~(a - 1); }

extern "C" void kernel_launch(void* const* d_in, const int* in_sizes, int n_in,
                              void* d_out, int out_size, void* d_ws, size_t ws_size,
                              hipStream_t stream)
{
    const float* R       = (const float*)d_in[0];
    const int*   Z       = (const int*)  d_in[1];
    const int*   nbr     = (const int*)  d_in[2];
    const float* offsets = (const float*)d_in[4];
    const float* emb     = (const float*)d_in[5];
    const float* W1      = (const float*)d_in[6];
    const float* b1      = (const float*)d_in[7];
    const float* W2      = (const float*)d_in[8];
    const float* b2      = (const float*)d_in[9];
    const float* W3      = (const float*)d_in[10];
    const float* b3      = (const float*)d_in[11];

    int natoms = in_sizes[0] / 3;
    int npairs = in_sizes[2] / 2;
    int Mpad = ((natoms + 127) / 128) * 128;

    char* ws = (char*)d_ws;
    size_t off = 0;
    int* counts = (int*)(ws + off); off = align_up(off + natoms*4, 256);
    int* offs   = (int*)(ws + off); off = align_up(off + natoms*4, 256);
    int* cursor = (int*)(ws + off); off = align_up(off + natoms*4, 256);
    int* sorted = (int*)(ws + off); off = align_up(off + (size_t)npairs*4, 256);
    float* pairdata = (float*)(ws + off); off = align_up(off + (size_t)npairs*8*4, 256);
    __hip_bfloat16* W1t   = (__hip_bfloat16*)(ws + off); off = align_up(off + (size_t)UNITS*KP1*2, 256);
    __hip_bfloat16* W2t   = (__hip_bfloat16*)(ws + off); off = align_up(off + (size_t)UNITS*UNITS*2, 256);
    __hip_bfloat16* feats = (__hip_bfloat16*)(ws + off); off = align_up(off + (size_t)Mpad*KP1*2, 256);
    __hip_bfloat16* h1    = (__hip_bfloat16*)(ws + off); off = align_up(off + (size_t)Mpad*UNITS*2, 256);

    hipMemsetAsync(counts, 0, (size_t)natoms * sizeof(int), stream);
    hipMemsetAsync(d_out, 0, (size_t)natoms * sizeof(float), stream);

    int pgrid = (npairs + 255) / 256;
    hist_kernel<<<dim3(pgrid), 256, 0, stream>>>(R, nbr, offsets, counts, npairs);
    scan_kernel<<<dim3(1), 1024, 0, stream>>>(counts, offs, cursor, natoms);
    scatter_kernel<<<dim3(pgrid), 256, 0, stream>>>(R, nbr, offsets, cursor, sorted, npairs);

    prep_w_t<<<dim3((UNITS*KP1 + 255)/256), 256, 0, stream>>>(W1, W1t, NFEAT, UNITS, KP1);
    prep_w_t<<<dim3((UNITS*UNITS + 255)/256), 256, 0, stream>>>(W2, W2t, UNITS, UNITS, UNITS);

    pair_compute_kernel<<<dim3(pgrid), 256, 0, stream>>>(
        R, Z, nbr, offsets, emb, sorted, &cursor[natoms - 1], pairdata, npairs);

    moment_feat_kernel<<<dim3((natoms + 3) / 4), 256, 0, stream>>>(
        pairdata, offs, counts, feats, natoms);

    float a1 = 1.0f / sqrtf((float)NFEAT);
    float a2 = 1.0f / sqrtf((float)UNITS);
    dim3 ggrid(Mpad / 128, UNITS / 128);
    gemm_mfma_swish<<<ggrid, 256, 0, stream>>>(
        feats, W1t, b1, h1, nullptr, nullptr, KP1, natoms, a1, 0.f, 0);
    gemm_mfma_swish<<<ggrid, 256, 0, stream>>>(
        h1, W2t, b2, nullptr, W3, (float*)d_out, UNITS, natoms, a2, a2, 1);

    finalize_kernel<<<dim3((natoms + 255) / 256), 256, 0, stream>>>(
        (float*)d_out, Z, b3, natoms);
}

// Round 5
// 279.601 us; speedup vs baseline: 5.7870x; 1.0127x over previous
//
#include <hip/hip_runtime.h>
#include <hip/hip_bf16.h>
#include <cmath>

#define NSP 119
#define UNITS 512
#define NFEAT 360
#define KP1 384          // NFEAT padded to multiple of 32

typedef __attribute__((ext_vector_type(8))) short short8;
typedef __attribute__((ext_vector_type(4))) float floatx4;

// ---------- constant index tables ----------
__constant__ int T2I[15] = {0,1,1,2,2,2,3,3,3,3,4,4,4,4,4};
__constant__ int T2J[15] = {0,0,1,0,1,2,0,1,2,3,0,1,2,3,4};
__constant__ int T3A[35] = {0, 1,1,1, 2,2,2,2,2,2, 3,3,3,3,3,3,3,3,3,3, 4,4,4,4,4,4,4,4,4,4,4,4,4,4,4};
__constant__ int T3B[35] = {0, 0,1,1, 0,1,1,2,2,2, 0,1,1,2,2,2,3,3,3,3, 0,1,1,2,2,2,3,3,3,3,4,4,4,4,4};
__constant__ int T3C[35] = {0, 0,0,1, 0,0,1,0,1,2, 0,0,1,0,1,2,0,1,2,3, 0,0,1,0,1,2,0,1,2,3,0,1,2,3,4};
__constant__ int P2X[6] = {0,1,1,2,2,2};
__constant__ int P2Y[6] = {0,0,1,0,1,2};
__constant__ int P3X[10] = {0,1,1,1,2,2,2,2,2,2};
__constant__ int P3Y[10] = {0,0,1,1,0,1,1,2,2,2};
__constant__ int P3Z[10] = {0,0,0,1,0,0,1,0,1,2};

// ---------- phase 1a: histogram of in-cutoff pairs per center atom ----------
__global__ __launch_bounds__(256) void hist_kernel(
    const float* __restrict__ R, const int* __restrict__ nbr,
    const float* __restrict__ offsets, int* __restrict__ counts, int npairs)
{
    int p = blockIdx.x * 256 + threadIdx.x;
    if (p >= npairs) return;
    int i = nbr[p];
    int j = nbr[npairs + p];
    float dx = R[3*j]   - R[3*i]   + offsets[3*p];
    float dy = R[3*j+1] - R[3*i+1] + offsets[3*p+1];
    float dz = R[3*j+2] - R[3*i+2] + offsets[3*p+2];
    float dr2 = dx*dx + dy*dy + dz*dz;
    if (dr2 < 36.0f) atomicAdd(&counts[i], 1);
}

// ---------- phase 1b: exclusive scan, single block, 32 items/thread ----------
__global__ __launch_bounds__(1024) void scan_kernel(
    const int* __restrict__ counts, int* __restrict__ offs,
    int* __restrict__ cursor, int n)
{
    int tid = threadIdx.x;
    int lane = tid & 63, wid = tid >> 6;
    int beg = tid * 32;
    int local[32];
    int s = 0;
    #pragma unroll
    for (int k = 0; k < 32; ++k) {
        int idx = beg + k;
        int v = (idx < n) ? counts[idx] : 0;
        local[k] = s;
        s += v;
    }
    int incl = s;
    #pragma unroll
    for (int off = 1; off < 64; off <<= 1) {
        int t = __shfl_up(incl, off, 64);
        if (lane >= off) incl += t;
    }
    __shared__ int wsum[16];
    if (lane == 63) wsum[wid] = incl;
    __syncthreads();
    if (tid < 16) {
        int v = wsum[tid];
        int inc2 = v;
        #pragma unroll
        for (int off = 1; off < 16; off <<= 1) {
            int t = __shfl_up(inc2, off, 64);
            if (tid >= off) inc2 += t;
        }
        wsum[tid] = inc2 - v;
    }
    __syncthreads();
    int base = wsum[wid] + (incl - s);
    #pragma unroll
    for (int k = 0; k < 32; ++k) {
        int idx = beg + k;
        if (idx < n) { int v = base + local[k]; offs[idx] = v; cursor[idx] = v; }
    }
}

// ---------- phase 1c: scatter pair indices into per-atom segments ----------
__global__ __launch_bounds__(256) void scatter_kernel(
    const float* __restrict__ R, const int* __restrict__ nbr,
    const float* __restrict__ offsets, int* __restrict__ cursor,
    int* __restrict__ sorted, int npairs)
{
    int p = blockIdx.x * 256 + threadIdx.x;
    if (p >= npairs) return;
    int i = nbr[p];
    int j = nbr[npairs + p];
    float dx = R[3*j]   - R[3*i]   + offsets[3*p];
    float dy = R[3*j+1] - R[3*i+1] + offsets[3*p+1];
    float dz = R[3*j+2] - R[3*i+2] + offsets[3*p+2];
    float dr2 = dx*dx + dy*dy + dz*dz;
    if (dr2 < 36.0f) {
        int pos = atomicAdd(&cursor[i], 1);
        sorted[pos] = p;
    }
}

// ---------- phase 1d: per-pair rad[5]+dn[3] records, fully pair-parallel ----------
__global__ __launch_bounds__(256) void pair_compute_kernel(
    const float* __restrict__ R, const int* __restrict__ Z,
    const int* __restrict__ nbr, const float* __restrict__ offsets,
    const float* __restrict__ emb, const int* __restrict__ sorted,
    const int* __restrict__ ntotal_ptr, float* __restrict__ pairdata, int npairs)
{
    int pos = blockIdx.x * 256 + threadIdx.x;
    if (pos >= *ntotal_ptr) return;
    int p = sorted[pos];
    int i = nbr[p], j = nbr[npairs + p];
    float dx = R[3*j]   - R[3*i]   + offsets[3*p];
    float dy = R[3*j+1] - R[3*i+1] + offsets[3*p+1];
    float dz = R[3*j+2] - R[3*i+2] + offsets[3*p+2];
    float dr = sqrtf(dx*dx + dy*dy + dz*dz);
    float inv = 1.0f / (dr + 1e-5f);
    float cutoff = 0.5f * (cosf(0.523598775598299f * dr) + 1.0f); // pi/R_MAX
    const float betta = 49.0f / 36.0f;
    const float rad_norm = expf(0.75f * logf(2.0f * betta / 3.14159265358979f));
    float basis[7];
    #pragma unroll
    for (int b = 0; b < 7; ++b) {
        float sh = 0.5f + b * (5.5f / 6.0f);
        float d = dr - sh;
        basis[b] = rad_norm * expf(-betta * d * d);
    }
    const float* e = emb + ((size_t)Z[j] * NSP + Z[i]) * 35;
    const float EMBN = 0.377964473009227f; // 1/sqrt(7)
    float rec[8];
    #pragma unroll
    for (int r = 0; r < 5; ++r) {
        float s = 0.f;
        #pragma unroll
        for (int b = 0; b < 7; ++b) s += e[r*7 + b] * basis[b];
        rec[r] = EMBN * s * cutoff;
    }
    rec[5] = dx * inv; rec[6] = dy * inv; rec[7] = dz * inv;
    float4* out = (float4*)(pairdata + (size_t)pos * 8);
    out[0] = make_float4(rec[0], rec[1], rec[2], rec[3]);
    out[1] = make_float4(rec[4], rec[5], rec[6], rec[7]);
}

// ---------- phase 2: one wave per atom: moments + contractions -> 360 bf16 feats ----------
#define SREC 12   // stage record stride (floats); [0..4]=rad, [5..7]=dn, [8]=1.0
__global__ __launch_bounds__(256) void moment_feat_kernel(
    const float* __restrict__ pairdata, const int* __restrict__ offs,
    const int* __restrict__ counts, __hip_bfloat16* __restrict__ feats, int natoms)
{
    int wv = threadIdx.x >> 6, lane = threadIdx.x & 63;
    int a = blockIdx.x * 4 + wv;
    __shared__ float stage[4][64][SREC];
    __shared__ float F[4][200];
    __shared__ float B2[4][135];
    __shared__ float A3[4][75];
    if (a >= natoms) return;   // wave-uniform; no __syncthreads in this kernel

    int start = offs[a], cnt = counts[a];

    int cr0, f00 = 8, f01 = 8, f02 = 8;
    if (lane < 5)       { cr0 = lane; }
    else if (lane < 20) { int c = lane - 5;  cr0 = c / 3; f00 = 5 + c % 3; }
    else if (lane < 50) { int c = lane - 20; cr0 = c / 6; int k = c % 6;
                          f00 = 5 + P2X[k]; f01 = 5 + P2Y[k]; }
    else                { int c = lane - 50; cr0 = c / 10; int k = c % 10;
                          f00 = 5 + P3X[k]; f01 = 5 + P3Y[k]; f02 = 5 + P3Z[k]; }
    int cr1 = 8, f10 = 8, f11 = 8, f12 = 8;
    if (lane < 36) { int c = 14 + lane; cr1 = c / 10; int k = c % 10;
                     f10 = 5 + P3X[k]; f11 = 5 + P3Y[k]; f12 = 5 + P3Z[k]; }

    float acc0 = 0.f, acc1 = 0.f;
    for (int base = 0; base < cnt; base += 64) {
        int m = min(64, cnt - base);
        if (lane < m) {
            const float4* pd = (const float4*)(pairdata + (size_t)(start + base + lane) * 8);
            float4 u = pd[0], v = pd[1];
            float* st = stage[wv][lane];
            ((float4*)st)[0] = u;
            ((float4*)st)[1] = v;
            st[8] = 1.0f;
        }
        __builtin_amdgcn_wave_barrier();
        for (int q = 0; q < m; ++q) {
            const float* s = stage[wv][q];
            acc0 += s[cr0] * s[f00] * s[f01] * s[f02];
            acc1 += s[cr1] * s[f10] * s[f11] * s[f12];
        }
        __builtin_amdgcn_wave_barrier();
    }
    float* raw = &stage[wv][0][0];
    __builtin_amdgcn_wave_barrier();
    raw[lane] = acc0;
    if (lane < 36) raw[64 + lane] = acc1;
    __builtin_amdgcn_wave_barrier();

    #pragma unroll
    for (int it = 0; it < 4; ++it) {
        int idx = lane + it * 64;
        if (idx < 200) {
            float v;
            if (idx < 20) {
                v = raw[idx];
            } else if (idx < 65) {
                int rel = idx - 20, r = rel / 9, q = rel % 9, x = q / 3, y = q % 3;
                int hi = max(x, y), lo = min(x, y);
                v = raw[20 + r*6 + hi*(hi+1)/2 + lo];
            } else {
                int rel = idx - 65, r = rel / 27, q = rel % 27;
                int x = q / 9, y = (q / 3) % 3, z = q % 3;
                int A = max(x, max(y, z)), C = min(x, min(y, z)), B = x + y + z - A - C;
                v = raw[50 + r*10 + A*(A+1)*(A+2)/6 + B*(B+1)/2 + C];
            }
            F[wv][idx] = v;
        }
    }
    __builtin_amdgcn_wave_barrier();

    const float* M0 = F[wv];
    const float* M1 = F[wv] + 5;    // [r*3+x]
    const float* M2 = F[wv] + 20;   // [r*9+x*3+y]
    const float* M3 = F[wv] + 65;   // [r*27+x*9+y*3+z]

    #pragma unroll
    for (int it = 0; it < 4; ++it) {
        int idx = lane + it * 64;
        if (idx < 135) {
            int p = idx / 9, zw = idx % 9, z = zw / 3, w_ = zw % 3;
            int r = T2I[p], s = T2J[p];
            float b = 0.f;
            for (int x = 0; x < 3; ++x)
                for (int y = 0; y < 3; ++y)
                    b += M3[r*27 + x*9 + y*3 + z] * M3[s*27 + x*9 + y*3 + w_];
            B2[wv][idx] = b;
        } else if (idx < 210) {
            int e = idx - 135;
            int rs = e / 3, z = e % 3;
            int r = rs / 5, s = rs % 5;
            float av = 0.f;
            for (int x = 0; x < 3; ++x)
                for (int y = 0; y < 3; ++y)
                    av += M3[r*27 + x*9 + y*3 + z] * M2[s*9 + x*3 + y];
            A3[wv][e] = av;
        }
    }
    __builtin_amdgcn_wave_barrier();

    __hip_bfloat16* out = feats + (size_t)a * KP1;
    for (int f = lane; f < NFEAT; f += 64) {
        float v = 0.f;
        if (f < 5) {
            v = M0[f];
        } else if (f < 20) {                 // c1
            int p = f - 5, r = T2I[p], s = T2J[p];
            for (int x = 0; x < 3; ++x) v += M1[r*3+x] * M1[s*3+x];
        } else if (f < 35) {                 // c2
            int p = f - 20, r = T2I[p], s = T2J[p];
            for (int q = 0; q < 9; ++q) v += M2[r*9+q] * M2[s*9+q];
        } else if (f < 50) {                 // c3
            int p = f - 35, r = T2I[p], s = T2J[p];
            for (int q = 0; q < 27; ++q) v += M3[r*27+q] * M3[s*27+q];
        } else if (f < 85) {                 // c4
            int q = f - 50, r = T3A[q], s = T3B[q], t = T3C[q];
            for (int x = 0; x < 3; ++x)
                for (int y = 0; y < 3; ++y)
                    for (int z = 0; z < 3; ++z)
                        v += M2[r*9+x*3+y] * M2[s*9+x*3+z] * M2[t*9+y*3+z];
        } else if (f < 160) {                // c5
            int q = f - 85, p = q / 5, t = q % 5, r = T2I[p], s = T2J[p];
            for (int x = 0; x < 3; ++x)
                for (int y = 0; y < 3; ++y)
                    v += M1[r*3+x] * M1[s*3+y] * M2[t*9+x*3+y];
        } else if (f < 235) {                // c6 via B2
            int q = f - 160, p = q / 5, t = q % 5;
            for (int zw = 0; zw < 9; ++zw)
                v += B2[wv][p*9 + zw] * M2[t*9 + zw];
        } else {                             // c7 via A3
            int q = f - 235, r = q / 25, s = (q / 5) % 5, t = q % 5;
            for (int z = 0; z < 3; ++z)
                v += A3[wv][(r*5+s)*3 + z] * M1[t*3 + z];
        }
        out[f] = __float2bfloat16(v);
    }
}

// ---------- weight transpose+pad to bf16: Wt[n*Kp+k] = W[k*N+n] ----------
__global__ __launch_bounds__(256) void prep_w_t(
    const float* __restrict__ W, __hip_bfloat16* __restrict__ Wt,
    int K, int N, int Kp)
{
    int idx = blockIdx.x * 256 + threadIdx.x;
    if (idx >= N * Kp) return;
    int n = idx / Kp, k = idx % Kp;
    float v = (k < K) ? W[(size_t)k * N + n] : 0.f;
    Wt[idx] = __float2bfloat16(v);
}

// ---------- bf16 MFMA GEMM, 128x64 tile, BK=32, reg-staged double-buffer ----------
// A: [Mpad x Kp] bf16 row-major. Bt: [512 x Kp] bf16 (N-major = B^T).
// LDS swizzle: chunk (row r, c) stored at pos r*4 + (c ^ ((r>>1)&3)) -> 2-way max.
// One __syncthreads per K-iter (double LDS buffer); global prefetch in registers.
__global__ __launch_bounds__(256) void gemm_mfma_swish(
    const __hip_bfloat16* __restrict__ A, const __hip_bfloat16* __restrict__ Bt,
    const float* __restrict__ bias, __hip_bfloat16* __restrict__ C,
    const float* __restrict__ w3, float* __restrict__ outacc,
    int Kp, int M, float alpha, float a3, int fuse)
{
    __shared__ float4 As[2][512];   // 128 rows x 4 chunks
    __shared__ float4 Bs[2][256];   // 64 rows x 4 chunks
    int tid = threadIdx.x;
    int wave = tid >> 6, lane = tid & 63;
    int quad = lane >> 4, l16 = lane & 15;
    int wm = wave >> 1, wn = wave & 1;   // 2x2 waves: 64-row x 32-col each
    int rowBase = blockIdx.x * 128;
    int colBase = blockIdx.y * 64;

    floatx4 acc[4][2] = {};

    // staging decode: thread -> (row, chunk)
    int rA0 = tid >> 2, cA = tid & 3;   // A rows 0..63
    int rA1 = rA0 + 64;                 // A rows 64..127
    int pA0 = rA0 * 4 + (cA ^ ((rA0 >> 1) & 3));
    int pA1 = rA1 * 4 + (cA ^ ((rA1 >> 1) & 3));
    int pB  = rA0 * 4 + (cA ^ ((rA0 >> 1) & 3));   // B rows 0..63, same pattern

    const char* pa0 = (const char*)(A  + (size_t)(rowBase + rA0) * Kp + cA * 8);
    const char* pa1 = (const char*)(A  + (size_t)(rowBase + rA1) * Kp + cA * 8);
    const char* pb  = (const char*)(Bt + (size_t)(colBase + rA0) * Kp + cA * 8);

    // fragment read positions
    int posA[4], posB[2];
    #pragma unroll
    for (int t = 0; t < 4; ++t) {
        int rr = wm * 64 + t * 16 + l16;
        posA[t] = rr * 4 + (quad ^ ((rr >> 1) & 3));
    }
    #pragma unroll
    for (int u = 0; u < 2; ++u) {
        int cc = wn * 32 + u * 16 + l16;
        posB[u] = cc * 4 + (quad ^ ((cc >> 1) & 3));
    }

    int nK = Kp >> 5;
    float4 ra0 = *(const float4*)pa0;
    float4 ra1 = *(const float4*)pa1;
    float4 rb  = *(const float4*)pb;

    for (int kt = 0; kt < nK; ++kt) {
        int buf = kt & 1;
        As[buf][pA0] = ra0;
        As[buf][pA1] = ra1;
        Bs[buf][pB]  = rb;
        __syncthreads();
        if (kt + 1 < nK) {
            int off = (kt + 1) << 6;   // 32 bf16 = 64 bytes
            ra0 = *(const float4*)(pa0 + off);
            ra1 = *(const float4*)(pa1 + off);
            rb  = *(const float4*)(pb  + off);
        }
        short8 af[4], bf[2];
        #pragma unroll
        for (int t = 0; t < 4; ++t) af[t] = *(const short8*)(As[buf] + posA[t]);
        #pragma unroll
        for (int u = 0; u < 2; ++u) bf[u] = *(const short8*)(Bs[buf] + posB[u]);
        #pragma unroll
        for (int t = 0; t < 4; ++t)
            #pragma unroll
            for (int u = 0; u < 2; ++u)
                acc[t][u] = __builtin_amdgcn_mfma_f32_16x16x32_bf16(
                    af[t], bf[u], acc[t][u], 0, 0, 0);
        // no trailing barrier: next iter writes the other LDS buffer, whose
        // readers all passed this iter's barrier already.
    }

    if (!fuse) {
        #pragma unroll
        for (int u = 0; u < 2; ++u) {
            int col = colBase + wn * 32 + u * 16 + l16;
            float bc = 0.1f * bias[col];
            #pragma unroll
            for (int t = 0; t < 4; ++t) {
                int row0 = rowBase + wm * 64 + t * 16 + quad * 4;
                #pragma unroll
                for (int r = 0; r < 4; ++r) {
                    float x = alpha * acc[t][u][r] + bc;
                    float v = x / (1.f + expf(-x));
                    C[(size_t)(row0 + r) * UNITS + col] = __float2bfloat16(v);
                }
            }
        }
    } else {
        float rowsum[4][4] = {};
        #pragma unroll
        for (int u = 0; u < 2; ++u) {
            int col = colBase + wn * 32 + u * 16 + l16;
            float bc = 0.1f * bias[col];
            float w3c = w3[col] * a3;
            #pragma unroll
            for (int t = 0; t < 4; ++t)
                #pragma unroll
                for (int r = 0; r < 4; ++r) {
                    float x = alpha * acc[t][u][r] + bc;
                    float v = x / (1.f + expf(-x));
                    rowsum[t][r] += v * w3c;
                }
        }
        #pragma unroll
        for (int t = 0; t < 4; ++t)
            #pragma unroll
            for (int r = 0; r < 4; ++r) {
                float s = rowsum[t][r];
                s += __shfl_xor(s, 1, 64);
                s += __shfl_xor(s, 2, 64);
                s += __shfl_xor(s, 4, 64);
                s += __shfl_xor(s, 8, 64);
                rowsum[t][r] = s;
            }
        if (l16 == 0) {
            #pragma unroll
            for (int t = 0; t < 4; ++t) {
                int row0 = rowBase + wm * 64 + t * 16 + quad * 4;
                #pragma unroll
                for (int r = 0; r < 4; ++r)
                    if (row0 + r < M) atomicAdd(&outacc[row0 + r], rowsum[t][r]);
            }
        }
    }
}

__global__ void finalize_kernel(float* __restrict__ out, const int* __restrict__ Z,
                                const float* __restrict__ b3, int natoms)
{
    int a = blockIdx.x * 256 + threadIdx.x;
    if (a >= natoms) return;
    float v = out[a] + 0.1f * b3[0];
    out[a] = (Z[a] > 0) ? v : 0.f;
}

static inline size_t align_up(size_t x, size_t a) { return (x + a - 1) & ~(a - 1); }

extern "C" void kernel_launch(void* const* d_in, const int* in_sizes, int n_in,
                              void* d_out, int out_size, void* d_ws, size_t ws_size,
                              hipStream_t stream)
{
    const float* R       = (const float*)d_in[0];
    const int*   Z       = (const int*)  d_in[1];
    const int*   nbr     = (const int*)  d_in[2];
    const float* offsets = (const float*)d_in[4];
    const float* emb     = (const float*)d_in[5];
    const float* W1      = (const float*)d_in[6];
    const float* b1      = (const float*)d_in[7];
    const float* W2      = (const float*)d_in[8];
    const float* b2      = (const float*)d_in[9];
    const float* W3      = (const float*)d_in[10];
    const float* b3      = (const float*)d_in[11];

    int natoms = in_sizes[0] / 3;
    int npairs = in_sizes[2] / 2;
    int Mpad = ((natoms + 127) / 128) * 128;

    char* ws = (char*)d_ws;
    size_t off = 0;
    int* counts = (int*)(ws + off); off = align_up(off + natoms*4, 256);
    int* offs   = (int*)(ws + off); off = align_up(off + natoms*4, 256);
    int* cursor = (int*)(ws + off); off = align_up(off + natoms*4, 256);
    int* sorted = (int*)(ws + off); off = align_up(off + (size_t)npairs*4, 256);
    float* pairdata = (float*)(ws + off); off = align_up(off + (size_t)npairs*8*4, 256);
    __hip_bfloat16* W1t   = (__hip_bfloat16*)(ws + off); off = align_up(off + (size_t)UNITS*KP1*2, 256);
    __hip_bfloat16* W2t   = (__hip_bfloat16*)(ws + off); off = align_up(off + (size_t)UNITS*UNITS*2, 256);
    __hip_bfloat16* feats = (__hip_bfloat16*)(ws + off); off = align_up(off + (size_t)Mpad*KP1*2, 256);
    __hip_bfloat16* h1    = (__hip_bfloat16*)(ws + off); off = align_up(off + (size_t)Mpad*UNITS*2, 256);

    hipMemsetAsync(counts, 0, (size_t)natoms * sizeof(int), stream);
    hipMemsetAsync(d_out, 0, (size_t)natoms * sizeof(float), stream);

    int pgrid = (npairs + 255) / 256;
    hist_kernel<<<dim3(pgrid), 256, 0, stream>>>(R, nbr, offsets, counts, npairs);
    scan_kernel<<<dim3(1), 1024, 0, stream>>>(counts, offs, cursor, natoms);
    scatter_kernel<<<dim3(pgrid), 256, 0, stream>>>(R, nbr, offsets, cursor, sorted, npairs);

    prep_w_t<<<dim3((UNITS*KP1 + 255)/256), 256, 0, stream>>>(W1, W1t, NFEAT, UNITS, KP1);
    prep_w_t<<<dim3((UNITS*UNITS + 255)/256), 256, 0, stream>>>(W2, W2t, UNITS, UNITS, UNITS);

    pair_compute_kernel<<<dim3(pgrid), 256, 0, stream>>>(
        R, Z, nbr, offsets, emb, sorted, &cursor[natoms - 1], pairdata, npairs);

    moment_feat_kernel<<<dim3((natoms + 3) / 4), 256, 0, stream>>>(
        pairdata, offs, counts, feats, natoms);

    float a1 = 1.0f / sqrtf((float)NFEAT);
    float a2 = 1.0f / sqrtf((float)UNITS);
    dim3 ggrid(Mpad / 128, UNITS / 64);
    gemm_mfma_swish<<<ggrid, 256, 0, stream>>>(
        feats, W1t, b1, h1, nullptr, nullptr, KP1, natoms, a1, 0.f, 0);
    gemm_mfma_swish<<<ggrid, 256, 0, stream>>>(
        h1, W2t, b2, nullptr, W3, (float*)d_out, UNITS, natoms, a2, a2, 1);

    finalize_kernel<<<dim3((natoms + 255) / 256), 256, 0, stream>>>(
        (float*)d_out, Z, b3, natoms);
}